// Round 1
// baseline (9266.248 us; speedup 1.0000x reference)
//
#include <hip/hip_runtime.h>
#include <cstdint>
#include <cstddef>

// Problem constants
#define NU_ 100000
#define NI_ 50000
#define F_ 256
#define H_ 8
#define HD_ 512
#define NE_ 300000
#define SLOPE_ 0.2f

typedef float f32x4 __attribute__((ext_vector_type(4)));
typedef __bf16 bf16x8 __attribute__((ext_vector_type(8)));
typedef unsigned short u16x8 __attribute__((ext_vector_type(8)));
typedef unsigned short u16x4 __attribute__((ext_vector_type(4)));

static __device__ __forceinline__ unsigned short f2bf_bits(float f) {
  unsigned u = __float_as_uint(f);
  u += 0x7fffu + ((u >> 16) & 1u);   // RNE
  return (unsigned short)(u >> 16);
}
static __device__ __forceinline__ float bf2f(unsigned short b) {
  return __uint_as_float(((unsigned)b) << 16);
}
// order-preserving float<->uint key for atomicMax
static __device__ __forceinline__ unsigned f2key(float f) {
  unsigned u = __float_as_uint(f);
  return (u & 0x80000000u) ? ~u : (u | 0x80000000u);
}
static __device__ __forceinline__ float key2f(unsigned k) {
  return __uint_as_float((k & 0x80000000u) ? (k ^ 0x80000000u) : ~k);
}

// ---------------- W [256][512] f32 -> Wt [512][256] bf16 ----------------
__global__ __launch_bounds__(256) void wconv_kernel(const float* __restrict__ W,
                                                    unsigned short* __restrict__ Wt) {
  int idx = blockIdx.x * 256 + threadIdx.x;   // 131072 elems
  int f = idx & 255, c = idx >> 8;
  Wt[idx] = f2bf_bits(W[(size_t)f * HD_ + c]);
}

// ---------------- fold[h][f] = sum_d W[f][h*64+d]*av[h*64+d] ----------------
__global__ __launch_bounds__(256) void fold_kernel(const float* __restrict__ W,
                                                   const float* __restrict__ av,
                                                   float* __restrict__ outf) {
  int idx = blockIdx.x * 256 + threadIdx.x;   // 2048 total
  int f = idx & 255, hh = idx >> 8;
  float acc = 0.f;
#pragma unroll 8
  for (int d = 0; d < 64; ++d) acc += W[(size_t)f * HD_ + hh * 64 + d] * av[hh * 64 + d];
  outf[hh * 256 + f] = acc;
}

// ---------------- per node: elA[n][h]=h[n].foldA[h], erB[n][h]=h[n].foldB[h] ---------
__global__ __launch_bounds__(256) void attvec_kernel(const float* __restrict__ h,
                                                     const float* __restrict__ foldA,
                                                     const float* __restrict__ foldB,
                                                     float* __restrict__ elA,
                                                     float* __restrict__ erB, int N) {
  __shared__ float sA[2048], sB[2048];   // [8][256]
  for (int i = threadIdx.x; i < 2048; i += 256) { sA[i] = foldA[i]; sB[i] = foldB[i]; }
  __syncthreads();
  int wave = threadIdx.x >> 6, lane = threadIdx.x & 63;
  int row = blockIdx.x * 4 + wave;
  if (row >= N) return;
  float aA[8] = {}, aB[8] = {};
#pragma unroll
  for (int j = 0; j < 4; ++j) {
    int f = lane + j * 64;
    float x = h[(size_t)row * F_ + f];
#pragma unroll
    for (int t = 0; t < 8; ++t) { aA[t] += x * sA[t * 256 + f]; aB[t] += x * sB[t * 256 + f]; }
  }
#pragma unroll
  for (int t = 0; t < 8; ++t) {
    for (int o = 32; o > 0; o >>= 1) {
      aA[t] += __shfl_down(aA[t], o);
      aB[t] += __shfl_down(aB[t], o);
    }
  }
  if (lane == 0) {
#pragma unroll
    for (int t = 0; t < 8; ++t) {
      elA[(size_t)row * 8 + t] = aA[t];
      erB[(size_t)row * 8 + t] = aB[t];
    }
  }
}

// ---------------- bf16 MFMA GEMM: C[M,512] = A[M,256] @ W, Wt=[512][256] bf16 --------
// OUT_MODE 0: C -> bf16 (ws, fs buffer). OUT_MODE 1: C+bias -> f32 (d_out, residual init).
template <int OUT_MODE>
__global__ __launch_bounds__(256) void gemm_kernel(const float* __restrict__ A,
                                                   const unsigned short* __restrict__ Bt,
                                                   void* __restrict__ Cout,
                                                   const float* __restrict__ bias, int M) {
  __shared__ unsigned short Alds[128][40];  // +8 pad: 80B row stride, 16B aligned
  __shared__ unsigned short Blds[128][40];
  int tid = threadIdx.x;
  int lane = tid & 63;
  int wave = tid >> 6;
  int wm = wave >> 1, wn = wave & 1;        // 2x2 waves -> 64x64 each
  int bid = blockIdx.x;
  int mt = bid >> 2, nt = bid & 3;          // consecutive blocks share the A tile (L2/L3)
  int bm = mt * 128, bn = nt * 128;
  f32x4 acc[4][4] = {};
  int lr = lane & 15;
  int kk = (lane >> 4) * 8;

  for (int k0 = 0; k0 < 256; k0 += 32) {
    // stage A: 128x32 f32 -> bf16 LDS
#pragma unroll
    for (int it = 0; it < 4; ++it) {
      int idx = tid + it * 256;            // 1024 float4 chunks
      int row = idx >> 3;
      int c4 = (idx & 7) << 2;
      f32x4 v = {};
      int gr = bm + row;
      if (gr < M) v = *(const f32x4*)&A[(size_t)gr * 256 + k0 + c4];
      u16x4 b;
      b.x = f2bf_bits(v.x); b.y = f2bf_bits(v.y); b.z = f2bf_bits(v.z); b.w = f2bf_bits(v.w);
      *(u16x4*)&Alds[row][c4] = b;
    }
    // stage B: 128 cols x 32 k bf16 (Wt row-major, same shape as A staging)
#pragma unroll
    for (int it = 0; it < 2; ++it) {
      int idx = tid + it * 256;            // 512 u16x8 chunks
      int row = idx >> 2;
      int c8 = (idx & 3) << 3;
      *(u16x8*)&Blds[row][c8] = *(const u16x8*)&Bt[(size_t)(bn + row) * 256 + k0 + c8];
    }
    __syncthreads();
    bf16x8 af[4], bfr[4];
#pragma unroll
    for (int m = 0; m < 4; ++m)
      af[m] = __builtin_bit_cast(bf16x8, *(const u16x8*)&Alds[wm * 64 + m * 16 + lr][kk]);
#pragma unroll
    for (int n = 0; n < 4; ++n)
      bfr[n] = __builtin_bit_cast(bf16x8, *(const u16x8*)&Blds[wn * 64 + n * 16 + lr][kk]);
#pragma unroll
    for (int m = 0; m < 4; ++m)
#pragma unroll
      for (int n = 0; n < 4; ++n)
        acc[m][n] = __builtin_amdgcn_mfma_f32_16x16x32_bf16(af[m], bfr[n], acc[m][n], 0, 0, 0);
    __syncthreads();
  }

  // epilogue: D row=(lane>>4)*4+r, col=lane&15  [verified layout]
  int rg = (lane >> 4) * 4;
#pragma unroll
  for (int m = 0; m < 4; ++m) {
#pragma unroll
    for (int r = 0; r < 4; ++r) {
      int row = bm + wm * 64 + m * 16 + rg + r;
      if (row >= M) continue;
#pragma unroll
      for (int n = 0; n < 4; ++n) {
        int col = bn + wn * 64 + n * 16 + lr;
        float v = acc[m][n][r];
        if (OUT_MODE == 1)
          ((float*)Cout)[(size_t)row * HD_ + col] = v + bias[col];
        else
          ((unsigned short*)Cout)[(size_t)row * HD_ + col] = f2bf_bits(v);
      }
    }
  }
}

// ---------------- edge pass 1: val = leaky(el[src]+er[dst]); segment max ----------
__global__ __launch_bounds__(256) void edge_max_kernel(const int* __restrict__ src,
                                                       const int* __restrict__ dst,
                                                       const float* __restrict__ el,
                                                       const float* __restrict__ er,
                                                       float* __restrict__ val,
                                                       unsigned* __restrict__ mkey, int E) {
  int e = blockIdx.x * 256 + threadIdx.x;
  if (e >= E) return;
  int se = src[e], de = dst[e];
  const f32x4* pl = (const f32x4*)&el[(size_t)se * 8];
  const f32x4* pr = (const f32x4*)&er[(size_t)de * 8];
  f32x4 v0 = pl[0] + pr[0];
  f32x4 v1 = pl[1] + pr[1];
#pragma unroll
  for (int t = 0; t < 4; ++t) {
    v0[t] = v0[t] > 0.f ? v0[t] : SLOPE_ * v0[t];
    v1[t] = v1[t] > 0.f ? v1[t] : SLOPE_ * v1[t];
  }
  *(f32x4*)&val[(size_t)e * 8] = v0;
  *(f32x4*)&val[(size_t)e * 8 + 4] = v1;
#pragma unroll
  for (int t = 0; t < 4; ++t) {
    atomicMax(&mkey[(size_t)de * 8 + t], f2key(v0[t]));
    atomicMax(&mkey[(size_t)de * 8 + 4 + t], f2key(v1[t]));
  }
}

// ---------------- edge pass 2: ex = exp(val - m[dst]); segment sum ----------------
__global__ __launch_bounds__(256) void edge_exp_kernel(const int* __restrict__ dst,
                                                       float* __restrict__ val,
                                                       const unsigned* __restrict__ mkey,
                                                       float* __restrict__ s, int E) {
  int e = blockIdx.x * 256 + threadIdx.x;
  if (e >= E) return;
  int de = dst[e];
#pragma unroll
  for (int t = 0; t < 8; ++t) {
    float m = key2f(mkey[(size_t)de * 8 + t]);
    float x = __expf(val[(size_t)e * 8 + t] - m);
    val[(size_t)e * 8 + t] = x;
    atomicAdd(&s[(size_t)de * 8 + t], x);
  }
}

// ---------------- edge pass 3: out[dst] += (ex/s[dst]) * fs[src]  (wave per edge) ----
__global__ __launch_bounds__(256) void scatter_kernel(const int* __restrict__ src,
                                                      const int* __restrict__ dst,
                                                      const float* __restrict__ ex,
                                                      const float* __restrict__ s,
                                                      const unsigned short* __restrict__ fs,
                                                      float* __restrict__ out, int E) {
  int wid = (blockIdx.x << 2) + (threadIdx.x >> 6);
  if (wid >= E) return;
  int lane = threadIdx.x & 63;
  int se = src[wid], de = dst[wid];
  int hh = lane >> 3;   // 8 lanes per head, 8 elems per lane
  float a = ex[(size_t)wid * 8 + hh] / s[(size_t)de * 8 + hh];
  u16x8 v = *(const u16x8*)&fs[(size_t)se * HD_ + lane * 8];
  float* op = &out[(size_t)de * HD_ + lane * 8];
#pragma unroll
  for (int j = 0; j < 8; ++j) atomicAdd(&op[j], a * bf2f((unsigned short)v[j]));
}

// =====================================================================================
extern "C" void kernel_launch(void* const* d_in, const int* in_sizes, int n_in,
                              void* d_out, int out_size, void* d_ws, size_t ws_size,
                              hipStream_t stream) {
  const float* h_user    = (const float*)d_in[0];
  const float* h_item    = (const float*)d_in[1];
  const int*   src_u2i   = (const int*)d_in[2];
  const int*   dst_u2i   = (const int*)d_in[3];
  const int*   src_i2u   = (const int*)d_in[4];
  const int*   dst_i2u   = (const int*)d_in[5];
  const float* W_src_u2i = (const float*)d_in[6];
  const float* W_dst_u2i = (const float*)d_in[7];
  const float* al_u2i    = (const float*)d_in[8];
  const float* ar_u2i    = (const float*)d_in[9];
  const float* bias_u2i  = (const float*)d_in[10];
  const float* W_res_u2i = (const float*)d_in[11];
  const float* W_src_i2u = (const float*)d_in[12];
  const float* W_dst_i2u = (const float*)d_in[13];
  const float* al_i2u    = (const float*)d_in[14];
  const float* ar_i2u    = (const float*)d_in[15];
  const float* bias_i2u  = (const float*)d_in[16];
  const float* W_res_i2u = (const float*)d_in[17];

  float* out_user = (float*)d_out;                       // [NU,512]
  float* out_item = (float*)d_out + (size_t)NU_ * HD_;   // [NI,512]

  char* ws = (char*)d_ws;
  size_t off = 0;
  auto take = [&](size_t bytes) -> char* {
    char* p = ws + off;
    off += (bytes + 255) & ~(size_t)255;
    return p;
  };
  unsigned short* fs_u2i     = (unsigned short*)take((size_t)NU_ * HD_ * 2);
  unsigned short* fs_i2u     = (unsigned short*)take((size_t)NI_ * HD_ * 2);
  unsigned short* Wt_src_u2i = (unsigned short*)take((size_t)HD_ * F_ * 2);
  unsigned short* Wt_res_u2i = (unsigned short*)take((size_t)HD_ * F_ * 2);
  unsigned short* Wt_src_i2u = (unsigned short*)take((size_t)HD_ * F_ * 2);
  unsigned short* Wt_res_i2u = (unsigned short*)take((size_t)HD_ * F_ * 2);
  float* wl_u2i = (float*)take(2048 * 4);
  float* wr_u2i = (float*)take(2048 * 4);
  float* wl_i2u = (float*)take(2048 * 4);
  float* wr_i2u = (float*)take(2048 * 4);
  float* el_u2i = (float*)take((size_t)NU_ * 8 * 4);
  float* er_u2i = (float*)take((size_t)NI_ * 8 * 4);
  float* el_i2u = (float*)take((size_t)NI_ * 8 * 4);
  float* er_i2u = (float*)take((size_t)NU_ * 8 * 4);
  // zero-block (contiguous, all sizes multiple of 256B): mkey_u2i, s_u2i, mkey_i2u, s_i2u
  unsigned* mkey_u2i = (unsigned*)take((size_t)NI_ * 8 * 4);
  float*    s_u2i    = (float*)take((size_t)NI_ * 8 * 4);
  unsigned* mkey_i2u = (unsigned*)take((size_t)NU_ * 8 * 4);
  float*    s_i2u    = (float*)take((size_t)NU_ * 8 * 4);
  float* val_u2i = (float*)take((size_t)NE_ * 8 * 4);
  float* val_i2u = (float*)take((size_t)NE_ * 8 * 4);

  hipMemsetAsync(mkey_u2i, 0, (size_t)(NI_ * 16 + NU_ * 16) * 4, stream);

  // weights: transpose+bf16 convert, and attention-vector folds
  wconv_kernel<<<512, 256, 0, stream>>>(W_src_u2i, Wt_src_u2i);
  wconv_kernel<<<512, 256, 0, stream>>>(W_res_u2i, Wt_res_u2i);
  wconv_kernel<<<512, 256, 0, stream>>>(W_src_i2u, Wt_src_i2u);
  wconv_kernel<<<512, 256, 0, stream>>>(W_res_i2u, Wt_res_i2u);
  fold_kernel<<<8, 256, 0, stream>>>(W_src_u2i, al_u2i, wl_u2i);
  fold_kernel<<<8, 256, 0, stream>>>(W_dst_u2i, ar_u2i, wr_u2i);
  fold_kernel<<<8, 256, 0, stream>>>(W_src_i2u, al_i2u, wl_i2u);
  fold_kernel<<<8, 256, 0, stream>>>(W_dst_i2u, ar_i2u, wr_i2u);

  // el/er: users need (el_u2i, er_i2u), items need (el_i2u, er_u2i)
  attvec_kernel<<<(NU_ + 3) / 4, 256, 0, stream>>>(h_user, wl_u2i, wr_i2u, el_u2i, er_i2u, NU_);
  attvec_kernel<<<(NI_ + 3) / 4, 256, 0, stream>>>(h_item, wl_i2u, wr_u2i, el_i2u, er_u2i, NI_);

  // GEMMs: fs -> ws (bf16); res+bias -> d_out (f32, output initializer)
  constexpr int MT_U = (NU_ + 127) / 128;  // 782
  constexpr int MT_I = (NI_ + 127) / 128;  // 391
  gemm_kernel<0><<<MT_U * 4, 256, 0, stream>>>(h_user, Wt_src_u2i, fs_u2i, nullptr, NU_);
  gemm_kernel<0><<<MT_I * 4, 256, 0, stream>>>(h_item, Wt_src_i2u, fs_i2u, nullptr, NI_);
  gemm_kernel<1><<<MT_I * 4, 256, 0, stream>>>(h_item, Wt_res_u2i, out_item, bias_u2i, NI_);
  gemm_kernel<1><<<MT_U * 4, 256, 0, stream>>>(h_user, Wt_res_i2u, out_user, bias_i2u, NU_);

  // edge softmax + scatter
  constexpr int EB = (NE_ + 255) / 256;
  edge_max_kernel<<<EB, 256, 0, stream>>>(src_u2i, dst_u2i, el_u2i, er_u2i, val_u2i, mkey_u2i, NE_);
  edge_max_kernel<<<EB, 256, 0, stream>>>(src_i2u, dst_i2u, el_i2u, er_i2u, val_i2u, mkey_i2u, NE_);
  edge_exp_kernel<<<EB, 256, 0, stream>>>(dst_u2i, val_u2i, mkey_u2i, s_u2i, NE_);
  edge_exp_kernel<<<EB, 256, 0, stream>>>(dst_i2u, val_i2u, mkey_i2u, s_i2u, NE_);
  scatter_kernel<<<NE_ / 4, 256, 0, stream>>>(src_u2i, dst_u2i, val_u2i, s_u2i, fs_u2i, out_item, NE_);
  scatter_kernel<<<NE_ / 4, 256, 0, stream>>>(src_i2u, dst_i2u, val_i2u, s_i2u, fs_i2u, out_user, NE_);
}

// Round 2
// 1609.684 us; speedup vs baseline: 5.7566x; 5.7566x over previous
//
#include <hip/hip_runtime.h>
#include <cstdint>
#include <cstddef>

// Problem constants
#define NU_ 100000
#define NI_ 50000
#define F_ 256
#define H_ 8
#define HD_ 512
#define NE_ 300000
#define SLOPE_ 0.2f

typedef float f32x4 __attribute__((ext_vector_type(4)));
typedef __bf16 bf16x8 __attribute__((ext_vector_type(8)));
typedef unsigned short u16x8 __attribute__((ext_vector_type(8)));
typedef unsigned short u16x4 __attribute__((ext_vector_type(4)));

static __device__ __forceinline__ unsigned short f2bf_bits(float f) {
  unsigned u = __float_as_uint(f);
  u += 0x7fffu + ((u >> 16) & 1u);   // RNE
  return (unsigned short)(u >> 16);
}
static __device__ __forceinline__ float bf2f(unsigned short b) {
  return __uint_as_float(((unsigned)b) << 16);
}
// order-preserving float<->uint key for atomicMax
static __device__ __forceinline__ unsigned f2key(float f) {
  unsigned u = __float_as_uint(f);
  return (u & 0x80000000u) ? ~u : (u | 0x80000000u);
}
static __device__ __forceinline__ float key2f(unsigned k) {
  return __uint_as_float((k & 0x80000000u) ? (k ^ 0x80000000u) : ~k);
}

// ---------------- W [256][512] f32 -> Wt [512][256] bf16 ----------------
__global__ __launch_bounds__(256) void wconv_kernel(const float* __restrict__ W,
                                                    unsigned short* __restrict__ Wt) {
  int idx = blockIdx.x * 256 + threadIdx.x;   // 131072 elems
  int f = idx & 255, c = idx >> 8;
  Wt[idx] = f2bf_bits(W[(size_t)f * HD_ + c]);
}

// ---------------- fold[h][f] = sum_d W[f][h*64+d]*av[h*64+d] ----------------
__global__ __launch_bounds__(256) void fold_kernel(const float* __restrict__ W,
                                                   const float* __restrict__ av,
                                                   float* __restrict__ outf) {
  int idx = blockIdx.x * 256 + threadIdx.x;   // 2048 total
  int f = idx & 255, hh = idx >> 8;
  float acc = 0.f;
#pragma unroll 8
  for (int d = 0; d < 64; ++d) acc += W[(size_t)f * HD_ + hh * 64 + d] * av[hh * 64 + d];
  outf[hh * 256 + f] = acc;
}

// ---------------- per node: elA[n][h]=h[n].foldA[h], erB[n][h]=h[n].foldB[h] ---------
__global__ __launch_bounds__(256) void attvec_kernel(const float* __restrict__ h,
                                                     const float* __restrict__ foldA,
                                                     const float* __restrict__ foldB,
                                                     float* __restrict__ elA,
                                                     float* __restrict__ erB, int N) {
  __shared__ float sA[2048], sB[2048];   // [8][256]
  for (int i = threadIdx.x; i < 2048; i += 256) { sA[i] = foldA[i]; sB[i] = foldB[i]; }
  __syncthreads();
  int wave = threadIdx.x >> 6, lane = threadIdx.x & 63;
  int row = blockIdx.x * 4 + wave;
  if (row >= N) return;
  float aA[8] = {}, aB[8] = {};
#pragma unroll
  for (int j = 0; j < 4; ++j) {
    int f = lane + j * 64;
    float x = h[(size_t)row * F_ + f];
#pragma unroll
    for (int t = 0; t < 8; ++t) { aA[t] += x * sA[t * 256 + f]; aB[t] += x * sB[t * 256 + f]; }
  }
#pragma unroll
  for (int t = 0; t < 8; ++t) {
    for (int o = 32; o > 0; o >>= 1) {
      aA[t] += __shfl_down(aA[t], o);
      aB[t] += __shfl_down(aB[t], o);
    }
  }
  if (lane == 0) {
#pragma unroll
    for (int t = 0; t < 8; ++t) {
      elA[(size_t)row * 8 + t] = aA[t];
      erB[(size_t)row * 8 + t] = aB[t];
    }
  }
}

// ---------------- bf16 MFMA GEMM: C[M,512] = A[M,256] @ W, Wt=[512][256] bf16 --------
// OUT_MODE 0: C -> bf16 (ws, fs buffer). OUT_MODE 1: C+bias -> f32 (d_out, residual init).
template <int OUT_MODE>
__global__ __launch_bounds__(256) void gemm_kernel(const float* __restrict__ A,
                                                   const unsigned short* __restrict__ Bt,
                                                   void* __restrict__ Cout,
                                                   const float* __restrict__ bias, int M) {
  __shared__ unsigned short Alds[128][40];  // +8 pad: 80B row stride, 16B aligned
  __shared__ unsigned short Blds[128][40];
  int tid = threadIdx.x;
  int lane = tid & 63;
  int wave = tid >> 6;
  int wm = wave >> 1, wn = wave & 1;        // 2x2 waves -> 64x64 each
  int bid = blockIdx.x;
  int mt = bid >> 2, nt = bid & 3;          // consecutive blocks share the A tile (L2/L3)
  int bm = mt * 128, bn = nt * 128;
  f32x4 acc[4][4] = {};
  int lr = lane & 15;
  int kk = (lane >> 4) * 8;

  for (int k0 = 0; k0 < 256; k0 += 32) {
    // stage A: 128x32 f32 -> bf16 LDS
#pragma unroll
    for (int it = 0; it < 4; ++it) {
      int idx = tid + it * 256;            // 1024 float4 chunks
      int row = idx >> 3;
      int c4 = (idx & 7) << 2;
      f32x4 v = {};
      int gr = bm + row;
      if (gr < M) v = *(const f32x4*)&A[(size_t)gr * 256 + k0 + c4];
      u16x4 b;
      b.x = f2bf_bits(v.x); b.y = f2bf_bits(v.y); b.z = f2bf_bits(v.z); b.w = f2bf_bits(v.w);
      *(u16x4*)&Alds[row][c4] = b;
    }
    // stage B: 128 cols x 32 k bf16 (Wt row-major, same shape as A staging)
#pragma unroll
    for (int it = 0; it < 2; ++it) {
      int idx = tid + it * 256;            // 512 u16x8 chunks
      int row = idx >> 2;
      int c8 = (idx & 3) << 3;
      *(u16x8*)&Blds[row][c8] = *(const u16x8*)&Bt[(size_t)(bn + row) * 256 + k0 + c8];
    }
    __syncthreads();
    bf16x8 af[4], bfr[4];
#pragma unroll
    for (int m = 0; m < 4; ++m)
      af[m] = __builtin_bit_cast(bf16x8, *(const u16x8*)&Alds[wm * 64 + m * 16 + lr][kk]);
#pragma unroll
    for (int n = 0; n < 4; ++n)
      bfr[n] = __builtin_bit_cast(bf16x8, *(const u16x8*)&Blds[wn * 64 + n * 16 + lr][kk]);
#pragma unroll
    for (int m = 0; m < 4; ++m)
#pragma unroll
      for (int n = 0; n < 4; ++n)
        acc[m][n] = __builtin_amdgcn_mfma_f32_16x16x32_bf16(af[m], bfr[n], acc[m][n], 0, 0, 0);
    __syncthreads();
  }

  // epilogue: D row=(lane>>4)*4+r, col=lane&15  [verified layout]
  int rg = (lane >> 4) * 4;
#pragma unroll
  for (int m = 0; m < 4; ++m) {
#pragma unroll
    for (int r = 0; r < 4; ++r) {
      int row = bm + wm * 64 + m * 16 + rg + r;
      if (row >= M) continue;
#pragma unroll
      for (int n = 0; n < 4; ++n) {
        int col = bn + wn * 64 + n * 16 + lr;
        float v = acc[m][n][r];
        if (OUT_MODE == 1)
          ((float*)Cout)[(size_t)row * HD_ + col] = v + bias[col];
        else
          ((unsigned short*)Cout)[(size_t)row * HD_ + col] = f2bf_bits(v);
      }
    }
  }
}

// ---------------- edge pass 1: val = leaky(el[src]+er[dst]); segment max; deg histogram
__global__ __launch_bounds__(256) void edge_max_kernel(const int* __restrict__ src,
                                                       const int* __restrict__ dst,
                                                       const float* __restrict__ el,
                                                       const float* __restrict__ er,
                                                       float* __restrict__ val,
                                                       unsigned* __restrict__ mkey,
                                                       int* __restrict__ deg, int E) {
  int e = blockIdx.x * 256 + threadIdx.x;
  if (e >= E) return;
  int se = src[e], de = dst[e];
  const f32x4* pl = (const f32x4*)&el[(size_t)se * 8];
  const f32x4* pr = (const f32x4*)&er[(size_t)de * 8];
  f32x4 v0 = pl[0] + pr[0];
  f32x4 v1 = pl[1] + pr[1];
#pragma unroll
  for (int t = 0; t < 4; ++t) {
    v0[t] = v0[t] > 0.f ? v0[t] : SLOPE_ * v0[t];
    v1[t] = v1[t] > 0.f ? v1[t] : SLOPE_ * v1[t];
  }
  *(f32x4*)&val[(size_t)e * 8] = v0;
  *(f32x4*)&val[(size_t)e * 8 + 4] = v1;
#pragma unroll
  for (int t = 0; t < 4; ++t) {
    atomicMax(&mkey[(size_t)de * 8 + t], f2key(v0[t]));
    atomicMax(&mkey[(size_t)de * 8 + 4 + t], f2key(v1[t]));
  }
  atomicAdd(&deg[de], 1);
}

// ---------------- single-block exclusive scan over deg (n up to 150k) ----------------
__global__ __launch_bounds__(1024) void scan_kernel(const int* __restrict__ deg,
                                                    int* __restrict__ rowstart,
                                                    int* __restrict__ cursor, int n) {
  __shared__ int lds[1024];
  __shared__ int carry;
  int tid = threadIdx.x;
  if (tid == 0) carry = 0;
  __syncthreads();
  for (int base = 0; base < n; base += 8192) {
    int i0 = base + tid * 8;
    int v[8];
    int sum = 0;
#pragma unroll
    for (int j = 0; j < 8; ++j) {
      v[j] = (i0 + j < n) ? deg[i0 + j] : 0;
      sum += v[j];
    }
    lds[tid] = sum;
    __syncthreads();
    for (int o = 1; o < 1024; o <<= 1) {
      int t = (tid >= o) ? lds[tid - o] : 0;
      __syncthreads();
      lds[tid] += t;
      __syncthreads();
    }
    int exc = carry + lds[tid] - sum;
    int total = lds[1023];
    int run = exc;
#pragma unroll
    for (int j = 0; j < 8; ++j) {
      if (i0 + j < n) { rowstart[i0 + j] = run; cursor[i0 + j] = run; }
      run += v[j];
    }
    __syncthreads();
    if (tid == 0) carry += total;
    __syncthreads();
  }
  if (tid == 0) rowstart[n] = carry;
}

// ---------------- edge pass 2: ex = exp(val - m[dst]); segment sum; CSR bin ----------
__global__ __launch_bounds__(256) void edge_exp_kernel(const int* __restrict__ dst,
                                                       float* __restrict__ val,
                                                       const unsigned* __restrict__ mkey,
                                                       float* __restrict__ s,
                                                       int* __restrict__ cursor,
                                                       int* __restrict__ eids, int E) {
  int e = blockIdx.x * 256 + threadIdx.x;
  if (e >= E) return;
  int de = dst[e];
#pragma unroll
  for (int t = 0; t < 8; ++t) {
    float m = key2f(mkey[(size_t)de * 8 + t]);
    float x = __expf(val[(size_t)e * 8 + t] - m);
    val[(size_t)e * 8 + t] = x;
    atomicAdd(&s[(size_t)de * 8 + t], x);
  }
  int pos = atomicAdd(&cursor[de], 1);
  eids[pos] = e;
}

// ---------------- edge pass 3: wave per dst node: out[n] += sum_e (ex/s)*fs[src] -----
__global__ __launch_bounds__(256) void accum_kernel(const int* __restrict__ rowstart,
                                                    const int* __restrict__ eids,
                                                    const int* __restrict__ src,
                                                    const float* __restrict__ ex,
                                                    const float* __restrict__ s,
                                                    const unsigned short* __restrict__ fs,
                                                    float* __restrict__ out, int N) {
  int n = blockIdx.x * 4 + (threadIdx.x >> 6);
  if (n >= N) return;
  int lane = threadIdx.x & 63;
  int r0 = rowstart[n], r1 = rowstart[n + 1];
  if (r0 == r1) return;   // no edges: out keeps residual+bias
  int hh = lane >> 3;
  float inv = 1.f / s[(size_t)n * 8 + hh];
  float acc[8] = {};
  for (int k = r0; k < r1; ++k) {
    int e = eids[k];
    int se = src[e];
    float a = ex[(size_t)e * 8 + hh] * inv;
    u16x8 v = *(const u16x8*)&fs[(size_t)se * HD_ + lane * 8];
#pragma unroll
    for (int j = 0; j < 8; ++j) acc[j] += a * bf2f((unsigned short)v[j]);
  }
  float* op = &out[(size_t)n * HD_ + lane * 8];
  f32x4 o0 = *(f32x4*)op, o1 = *(f32x4*)(op + 4);
#pragma unroll
  for (int j = 0; j < 4; ++j) { o0[j] += acc[j]; o1[j] += acc[4 + j]; }
  *(f32x4*)op = o0;
  *(f32x4*)(op + 4) = o1;
}

// =====================================================================================
extern "C" void kernel_launch(void* const* d_in, const int* in_sizes, int n_in,
                              void* d_out, int out_size, void* d_ws, size_t ws_size,
                              hipStream_t stream) {
  const float* h_user    = (const float*)d_in[0];
  const float* h_item    = (const float*)d_in[1];
  const int*   src_u2i   = (const int*)d_in[2];
  const int*   dst_u2i   = (const int*)d_in[3];
  const int*   src_i2u   = (const int*)d_in[4];
  const int*   dst_i2u   = (const int*)d_in[5];
  const float* W_src_u2i = (const float*)d_in[6];
  const float* W_dst_u2i = (const float*)d_in[7];
  const float* al_u2i    = (const float*)d_in[8];
  const float* ar_u2i    = (const float*)d_in[9];
  const float* bias_u2i  = (const float*)d_in[10];
  const float* W_res_u2i = (const float*)d_in[11];
  const float* W_src_i2u = (const float*)d_in[12];
  const float* W_dst_i2u = (const float*)d_in[13];
  const float* al_i2u    = (const float*)d_in[14];
  const float* ar_i2u    = (const float*)d_in[15];
  const float* bias_i2u  = (const float*)d_in[16];
  const float* W_res_i2u = (const float*)d_in[17];

  float* out_user = (float*)d_out;                       // [NU,512]
  float* out_item = (float*)d_out + (size_t)NU_ * HD_;   // [NI,512]

  char* ws = (char*)d_ws;
  size_t off = 0;
  auto take = [&](size_t bytes) -> char* {
    char* p = ws + off;
    off += (bytes + 255) & ~(size_t)255;
    return p;
  };
  unsigned short* fs_u2i     = (unsigned short*)take((size_t)NU_ * HD_ * 2);
  unsigned short* fs_i2u     = (unsigned short*)take((size_t)NI_ * HD_ * 2);
  unsigned short* Wt_src_u2i = (unsigned short*)take((size_t)HD_ * F_ * 2);
  unsigned short* Wt_res_u2i = (unsigned short*)take((size_t)HD_ * F_ * 2);
  unsigned short* Wt_src_i2u = (unsigned short*)take((size_t)HD_ * F_ * 2);
  unsigned short* Wt_res_i2u = (unsigned short*)take((size_t)HD_ * F_ * 2);
  float* wl_u2i = (float*)take(2048 * 4);
  float* wr_u2i = (float*)take(2048 * 4);
  float* wl_i2u = (float*)take(2048 * 4);
  float* wr_i2u = (float*)take(2048 * 4);
  float* el_u2i = (float*)take((size_t)NU_ * 8 * 4);
  float* er_u2i = (float*)take((size_t)NI_ * 8 * 4);
  float* el_i2u = (float*)take((size_t)NI_ * 8 * 4);
  float* er_i2u = (float*)take((size_t)NU_ * 8 * 4);
  // ---- zero block (contiguous): deg_all, mkey_u2i, s_u2i, mkey_i2u, s_i2u ----
  int*      deg_all  = (int*)take((size_t)(NI_ + NU_) * 4);
  unsigned* mkey_u2i = (unsigned*)take((size_t)NI_ * 8 * 4);
  float*    s_u2i    = (float*)take((size_t)NI_ * 8 * 4);
  unsigned* mkey_i2u = (unsigned*)take((size_t)NU_ * 8 * 4);
  float*    s_i2u    = (float*)take((size_t)NU_ * 8 * 4);
  size_t zero_bytes = (size_t)((char*)s_i2u + (size_t)NU_ * 8 * 4 - (char*)deg_all);
  // ---- end zero block ----
  int* rowstart_all = (int*)take((size_t)(NI_ + NU_ + 1) * 4);
  int* cursor_all   = (int*)take((size_t)(NI_ + NU_) * 4);
  int* eids_all     = (int*)take((size_t)2 * NE_ * 4);
  float* val_u2i = (float*)take((size_t)NE_ * 8 * 4);
  float* val_i2u = (float*)take((size_t)NE_ * 8 * 4);

  hipMemsetAsync(deg_all, 0, zero_bytes, stream);

  // weights: transpose+bf16 convert, and attention-vector folds
  wconv_kernel<<<512, 256, 0, stream>>>(W_src_u2i, Wt_src_u2i);
  wconv_kernel<<<512, 256, 0, stream>>>(W_res_u2i, Wt_res_u2i);
  wconv_kernel<<<512, 256, 0, stream>>>(W_src_i2u, Wt_src_i2u);
  wconv_kernel<<<512, 256, 0, stream>>>(W_res_i2u, Wt_res_i2u);
  fold_kernel<<<8, 256, 0, stream>>>(W_src_u2i, al_u2i, wl_u2i);
  fold_kernel<<<8, 256, 0, stream>>>(W_dst_u2i, ar_u2i, wr_u2i);
  fold_kernel<<<8, 256, 0, stream>>>(W_src_i2u, al_i2u, wl_i2u);
  fold_kernel<<<8, 256, 0, stream>>>(W_dst_i2u, ar_i2u, wr_i2u);

  // el/er: users need (el_u2i, er_i2u), items need (el_i2u, er_u2i)
  attvec_kernel<<<(NU_ + 3) / 4, 256, 0, stream>>>(h_user, wl_u2i, wr_i2u, el_u2i, er_i2u, NU_);
  attvec_kernel<<<(NI_ + 3) / 4, 256, 0, stream>>>(h_item, wl_i2u, wr_u2i, el_i2u, er_u2i, NI_);

  // GEMMs: fs -> ws (bf16); res+bias -> d_out (f32, output initializer)
  constexpr int MT_U = (NU_ + 127) / 128;  // 782
  constexpr int MT_I = (NI_ + 127) / 128;  // 391
  gemm_kernel<0><<<MT_U * 4, 256, 0, stream>>>(h_user, Wt_src_u2i, fs_u2i, nullptr, NU_);
  gemm_kernel<0><<<MT_I * 4, 256, 0, stream>>>(h_item, Wt_src_i2u, fs_i2u, nullptr, NI_);
  gemm_kernel<1><<<MT_I * 4, 256, 0, stream>>>(h_item, Wt_res_u2i, out_item, bias_u2i, NI_);
  gemm_kernel<1><<<MT_U * 4, 256, 0, stream>>>(h_user, Wt_res_i2u, out_user, bias_i2u, NU_);

  // edge softmax: pass 1 (max + degree histogram)
  constexpr int EB = (NE_ + 255) / 256;
  edge_max_kernel<<<EB, 256, 0, stream>>>(src_u2i, dst_u2i, el_u2i, er_u2i, val_u2i,
                                          mkey_u2i, deg_all, NE_);
  edge_max_kernel<<<EB, 256, 0, stream>>>(src_i2u, dst_i2u, el_i2u, er_i2u, val_i2u,
                                          mkey_i2u, deg_all + NI_, NE_);
  // CSR scan (items segment first, then users)
  scan_kernel<<<1, 1024, 0, stream>>>(deg_all, rowstart_all, cursor_all, NI_ + NU_);
  // pass 2: exp + segment-sum + CSR binning
  edge_exp_kernel<<<EB, 256, 0, stream>>>(dst_u2i, val_u2i, mkey_u2i, s_u2i,
                                          cursor_all, eids_all, NE_);
  edge_exp_kernel<<<EB, 256, 0, stream>>>(dst_i2u, val_i2u, mkey_i2u, s_i2u,
                                          cursor_all + NI_, eids_all, NE_);
  // pass 3: wave-per-node gather-accumulate (no atomics)
  accum_kernel<<<(NI_ + 3) / 4, 256, 0, stream>>>(rowstart_all, eids_all, src_u2i,
                                                  val_u2i, s_u2i, fs_u2i, out_item, NI_);
  accum_kernel<<<(NU_ + 3) / 4, 256, 0, stream>>>(rowstart_all + NI_, eids_all, src_i2u,
                                                  val_i2u, s_i2u, fs_i2u, out_user, NU_);
}

// Round 3
// 1400.609 us; speedup vs baseline: 6.6159x; 1.1493x over previous
//
#include <hip/hip_runtime.h>
#include <cstdint>
#include <cstddef>

// Problem constants
#define NU_ 100000
#define NI_ 50000
#define F_ 256
#define H_ 8
#define HD_ 512
#define NE_ 300000
#define SLOPE_ 0.2f

#define SCAN_N (NI_ + NU_)
#define SCAN_CHUNK 2048
#define SCAN_NB ((SCAN_N + SCAN_CHUNK - 1) / SCAN_CHUNK)  // 74

typedef float f32x4 __attribute__((ext_vector_type(4)));
typedef __bf16 bf16x8 __attribute__((ext_vector_type(8)));
typedef unsigned short u16x8 __attribute__((ext_vector_type(8)));
typedef unsigned short u16x4 __attribute__((ext_vector_type(4)));

static __device__ __forceinline__ unsigned short f2bf_bits(float f) {
  unsigned u = __float_as_uint(f);
  u += 0x7fffu + ((u >> 16) & 1u);   // RNE
  return (unsigned short)(u >> 16);
}
static __device__ __forceinline__ float bf2f(unsigned short b) {
  return __uint_as_float(((unsigned)b) << 16);
}
// order-preserving float<->uint key for atomicMax
static __device__ __forceinline__ unsigned f2key(float f) {
  unsigned u = __float_as_uint(f);
  return (u & 0x80000000u) ? ~u : (u | 0x80000000u);
}
static __device__ __forceinline__ float key2f(unsigned k) {
  return __uint_as_float((k & 0x80000000u) ? (k ^ 0x80000000u) : ~k);
}

// ---------------- W [256][512] f32 -> Wt [512][256] bf16 ----------------
__global__ __launch_bounds__(256) void wconv_kernel(const float* __restrict__ W,
                                                    unsigned short* __restrict__ Wt) {
  int idx = blockIdx.x * 256 + threadIdx.x;   // 131072 elems
  int f = idx & 255, c = idx >> 8;
  Wt[idx] = f2bf_bits(W[(size_t)f * HD_ + c]);
}

// ---------------- fold[h][f] = sum_d W[f][h*64+d]*av[h*64+d] ----------------
__global__ __launch_bounds__(256) void fold_kernel(const float* __restrict__ W,
                                                   const float* __restrict__ av,
                                                   float* __restrict__ outf) {
  int idx = blockIdx.x * 256 + threadIdx.x;   // 2048 total
  int f = idx & 255, hh = idx >> 8;
  float acc = 0.f;
#pragma unroll 8
  for (int d = 0; d < 64; ++d) acc += W[(size_t)f * HD_ + hh * 64 + d] * av[hh * 64 + d];
  outf[hh * 256 + f] = acc;
}

// ---------------- per node: elA[n][h]=h[n].foldA[h], erB[n][h]=h[n].foldB[h] ---------
__global__ __launch_bounds__(256) void attvec_kernel(const float* __restrict__ h,
                                                     const float* __restrict__ foldA,
                                                     const float* __restrict__ foldB,
                                                     float* __restrict__ elA,
                                                     float* __restrict__ erB, int N) {
  __shared__ float sA[2048], sB[2048];   // [8][256]
  for (int i = threadIdx.x; i < 2048; i += 256) { sA[i] = foldA[i]; sB[i] = foldB[i]; }
  __syncthreads();
  int wave = threadIdx.x >> 6, lane = threadIdx.x & 63;
  int row = blockIdx.x * 4 + wave;
  if (row >= N) return;
  float aA[8] = {}, aB[8] = {};
#pragma unroll
  for (int j = 0; j < 4; ++j) {
    int f = lane + j * 64;
    float x = h[(size_t)row * F_ + f];
#pragma unroll
    for (int t = 0; t < 8; ++t) { aA[t] += x * sA[t * 256 + f]; aB[t] += x * sB[t * 256 + f]; }
  }
#pragma unroll
  for (int t = 0; t < 8; ++t) {
    for (int o = 32; o > 0; o >>= 1) {
      aA[t] += __shfl_down(aA[t], o);
      aB[t] += __shfl_down(aB[t], o);
    }
  }
  if (lane == 0) {
#pragma unroll
    for (int t = 0; t < 8; ++t) {
      elA[(size_t)row * 8 + t] = aA[t];
      erB[(size_t)row * 8 + t] = aB[t];
    }
  }
}

// ---------------- bf16 MFMA GEMM: C[M,512] = A[M,256] @ W, Wt=[512][256] bf16 --------
// OUT_MODE 0: C -> bf16 (ws, fs buffer). OUT_MODE 1: C+bias -> f32 (d_out, residual init).
template <int OUT_MODE>
__global__ __launch_bounds__(256) void gemm_kernel(const float* __restrict__ A,
                                                   const unsigned short* __restrict__ Bt,
                                                   void* __restrict__ Cout,
                                                   const float* __restrict__ bias, int M) {
  __shared__ unsigned short Alds[128][40];  // +8 pad: 80B row stride, 16B aligned
  __shared__ unsigned short Blds[128][40];
  int tid = threadIdx.x;
  int lane = tid & 63;
  int wave = tid >> 6;
  int wm = wave >> 1, wn = wave & 1;        // 2x2 waves -> 64x64 each
  int bid = blockIdx.x;
  int mt = bid >> 2, nt = bid & 3;          // consecutive blocks share the A tile (L2/L3)
  int bm = mt * 128, bn = nt * 128;
  f32x4 acc[4][4] = {};
  int lr = lane & 15;
  int kk = (lane >> 4) * 8;

  for (int k0 = 0; k0 < 256; k0 += 32) {
    // stage A: 128x32 f32 -> bf16 LDS
#pragma unroll
    for (int it = 0; it < 4; ++it) {
      int idx = tid + it * 256;            // 1024 float4 chunks
      int row = idx >> 3;
      int c4 = (idx & 7) << 2;
      f32x4 v = {};
      int gr = bm + row;
      if (gr < M) v = *(const f32x4*)&A[(size_t)gr * 256 + k0 + c4];
      u16x4 b;
      b.x = f2bf_bits(v.x); b.y = f2bf_bits(v.y); b.z = f2bf_bits(v.z); b.w = f2bf_bits(v.w);
      *(u16x4*)&Alds[row][c4] = b;
    }
    // stage B: 128 cols x 32 k bf16 (Wt row-major, same shape as A staging)
#pragma unroll
    for (int it = 0; it < 2; ++it) {
      int idx = tid + it * 256;            // 512 u16x8 chunks
      int row = idx >> 2;
      int c8 = (idx & 3) << 3;
      *(u16x8*)&Blds[row][c8] = *(const u16x8*)&Bt[(size_t)(bn + row) * 256 + k0 + c8];
    }
    __syncthreads();
    bf16x8 af[4], bfr[4];
#pragma unroll
    for (int m = 0; m < 4; ++m)
      af[m] = __builtin_bit_cast(bf16x8, *(const u16x8*)&Alds[wm * 64 + m * 16 + lr][kk]);
#pragma unroll
    for (int n = 0; n < 4; ++n)
      bfr[n] = __builtin_bit_cast(bf16x8, *(const u16x8*)&Blds[wn * 64 + n * 16 + lr][kk]);
#pragma unroll
    for (int m = 0; m < 4; ++m)
#pragma unroll
      for (int n = 0; n < 4; ++n)
        acc[m][n] = __builtin_amdgcn_mfma_f32_16x16x32_bf16(af[m], bfr[n], acc[m][n], 0, 0, 0);
    __syncthreads();
  }

  // epilogue: D row=(lane>>4)*4+r, col=lane&15  [verified layout]
  int rg = (lane >> 4) * 4;
#pragma unroll
  for (int m = 0; m < 4; ++m) {
#pragma unroll
    for (int r = 0; r < 4; ++r) {
      int row = bm + wm * 64 + m * 16 + rg + r;
      if (row >= M) continue;
#pragma unroll
      for (int n = 0; n < 4; ++n) {
        int col = bn + wn * 64 + n * 16 + lr;
        float v = acc[m][n][r];
        if (OUT_MODE == 1)
          ((float*)Cout)[(size_t)row * HD_ + col] = v + bias[col];
        else
          ((unsigned short*)Cout)[(size_t)row * HD_ + col] = f2bf_bits(v);
      }
    }
  }
}

// ---------------- edge pass 1: val = leaky(el[src]+er[dst]); segment max; deg histogram
__global__ __launch_bounds__(256) void edge_max_kernel(const int* __restrict__ src,
                                                       const int* __restrict__ dst,
                                                       const float* __restrict__ el,
                                                       const float* __restrict__ er,
                                                       float* __restrict__ val,
                                                       unsigned* __restrict__ mkey,
                                                       int* __restrict__ deg, int E) {
  int e = blockIdx.x * 256 + threadIdx.x;
  if (e >= E) return;
  int se = src[e], de = dst[e];
  const f32x4* pl = (const f32x4*)&el[(size_t)se * 8];
  const f32x4* pr = (const f32x4*)&er[(size_t)de * 8];
  f32x4 v0 = pl[0] + pr[0];
  f32x4 v1 = pl[1] + pr[1];
#pragma unroll
  for (int t = 0; t < 4; ++t) {
    v0[t] = v0[t] > 0.f ? v0[t] : SLOPE_ * v0[t];
    v1[t] = v1[t] > 0.f ? v1[t] : SLOPE_ * v1[t];
  }
  *(f32x4*)&val[(size_t)e * 8] = v0;
  *(f32x4*)&val[(size_t)e * 8 + 4] = v1;
#pragma unroll
  for (int t = 0; t < 4; ++t) {
    atomicMax(&mkey[(size_t)de * 8 + t], f2key(v0[t]));
    atomicMax(&mkey[(size_t)de * 8 + 4 + t], f2key(v1[t]));
  }
  atomicAdd(&deg[de], 1);
}

// ---------------- two-level scan over deg (SCAN_N elements) ----------------
__global__ __launch_bounds__(256) void scan_reduce_kernel(const int* __restrict__ deg,
                                                          int* __restrict__ bsum) {
  __shared__ int lds[256];
  int tid = threadIdx.x;
  int base = blockIdx.x * SCAN_CHUNK + tid * 8;
  int sum = 0;
#pragma unroll
  for (int j = 0; j < 8; ++j) sum += (base + j < SCAN_N) ? deg[base + j] : 0;
  lds[tid] = sum;
  __syncthreads();
  for (int o = 128; o > 0; o >>= 1) {
    if (tid < o) lds[tid] += lds[tid + o];
    __syncthreads();
  }
  if (tid == 0) bsum[blockIdx.x] = lds[0];
}

__global__ __launch_bounds__(128) void scan_part_kernel(int* __restrict__ bsum, int nb) {
  // exclusive scan of bsum in place (nb <= 128), single block
  __shared__ int lds[128];
  int tid = threadIdx.x;
  int v = (tid < nb) ? bsum[tid] : 0;
  lds[tid] = v;
  __syncthreads();
  for (int o = 1; o < 128; o <<= 1) {
    int t = (tid >= o) ? lds[tid - o] : 0;
    __syncthreads();
    lds[tid] += t;
    __syncthreads();
  }
  if (tid < nb) bsum[tid] = lds[tid] - v;
}

__global__ __launch_bounds__(256) void scan_apply_kernel(const int* __restrict__ deg,
                                                         const int* __restrict__ bsum,
                                                         int* __restrict__ rowstart,
                                                         int* __restrict__ cursor) {
  __shared__ int lds[256];
  int tid = threadIdx.x;
  int base = blockIdx.x * SCAN_CHUNK + tid * 8;
  int v[8];
  int sum = 0;
#pragma unroll
  for (int j = 0; j < 8; ++j) {
    v[j] = (base + j < SCAN_N) ? deg[base + j] : 0;
    sum += v[j];
  }
  lds[tid] = sum;
  __syncthreads();
  for (int o = 1; o < 256; o <<= 1) {
    int t = (tid >= o) ? lds[tid - o] : 0;
    __syncthreads();
    lds[tid] += t;
    __syncthreads();
  }
  int run = bsum[blockIdx.x] + lds[tid] - sum;
#pragma unroll
  for (int j = 0; j < 8; ++j) {
    if (base + j < SCAN_N) { rowstart[base + j] = run; cursor[base + j] = run; }
    run += v[j];
  }
  if (blockIdx.x == 0 && tid == 0) rowstart[SCAN_N] = 2 * NE_;  // known total
}

// ---------------- edge pass 2: ex = exp(val - m[dst]); segment sum; CSR bin ----------
__global__ __launch_bounds__(256) void edge_exp_kernel(const int* __restrict__ dst,
                                                       float* __restrict__ val,
                                                       const unsigned* __restrict__ mkey,
                                                       float* __restrict__ s,
                                                       int* __restrict__ cursor,
                                                       int* __restrict__ eids, int E) {
  int e = blockIdx.x * 256 + threadIdx.x;
  if (e >= E) return;
  int de = dst[e];
#pragma unroll
  for (int t = 0; t < 8; ++t) {
    float m = key2f(mkey[(size_t)de * 8 + t]);
    float x = __expf(val[(size_t)e * 8 + t] - m);
    val[(size_t)e * 8 + t] = x;
    atomicAdd(&s[(size_t)de * 8 + t], x);
  }
  int pos = atomicAdd(&cursor[de], 1);
  eids[pos] = e;
}

// ---------------- edge pass 3: wave per dst node: out[n] += sum_e (ex/s)*fs[src] -----
__global__ __launch_bounds__(256) void accum_kernel(const int* __restrict__ rowstart,
                                                    const int* __restrict__ eids,
                                                    const int* __restrict__ src,
                                                    const float* __restrict__ ex,
                                                    const float* __restrict__ s,
                                                    const unsigned short* __restrict__ fs,
                                                    float* __restrict__ out, int N) {
  int n = blockIdx.x * 4 + (threadIdx.x >> 6);
  if (n >= N) return;
  int lane = threadIdx.x & 63;
  int r0 = rowstart[n], r1 = rowstart[n + 1];
  if (r0 == r1) return;   // no edges: out keeps residual+bias
  int hh = lane >> 3;
  float inv = 1.f / s[(size_t)n * 8 + hh];
  float acc[8] = {};
  for (int k = r0; k < r1; ++k) {
    int e = eids[k];
    int se = src[e];
    float a = ex[(size_t)e * 8 + hh] * inv;
    u16x8 v = *(const u16x8*)&fs[(size_t)se * HD_ + lane * 8];
#pragma unroll
    for (int j = 0; j < 8; ++j) acc[j] += a * bf2f((unsigned short)v[j]);
  }
  float* op = &out[(size_t)n * HD_ + lane * 8];
  f32x4 o0 = *(f32x4*)op, o1 = *(f32x4*)(op + 4);
#pragma unroll
  for (int j = 0; j < 4; ++j) { o0[j] += acc[j]; o1[j] += acc[4 + j]; }
  *(f32x4*)op = o0;
  *(f32x4*)(op + 4) = o1;
}

// =====================================================================================
extern "C" void kernel_launch(void* const* d_in, const int* in_sizes, int n_in,
                              void* d_out, int out_size, void* d_ws, size_t ws_size,
                              hipStream_t stream) {
  const float* h_user    = (const float*)d_in[0];
  const float* h_item    = (const float*)d_in[1];
  const int*   src_u2i   = (const int*)d_in[2];
  const int*   dst_u2i   = (const int*)d_in[3];
  const int*   src_i2u   = (const int*)d_in[4];
  const int*   dst_i2u   = (const int*)d_in[5];
  const float* W_src_u2i = (const float*)d_in[6];
  const float* W_dst_u2i = (const float*)d_in[7];
  const float* al_u2i    = (const float*)d_in[8];
  const float* ar_u2i    = (const float*)d_in[9];
  const float* bias_u2i  = (const float*)d_in[10];
  const float* W_res_u2i = (const float*)d_in[11];
  const float* W_src_i2u = (const float*)d_in[12];
  const float* W_dst_i2u = (const float*)d_in[13];
  const float* al_i2u    = (const float*)d_in[14];
  const float* ar_i2u    = (const float*)d_in[15];
  const float* bias_i2u  = (const float*)d_in[16];
  const float* W_res_i2u = (const float*)d_in[17];

  float* out_user = (float*)d_out;                       // [NU,512]
  float* out_item = (float*)d_out + (size_t)NU_ * HD_;   // [NI,512]

  char* ws = (char*)d_ws;
  size_t off = 0;
  auto take = [&](size_t bytes) -> char* {
    char* p = ws + off;
    off += (bytes + 255) & ~(size_t)255;
    return p;
  };
  unsigned short* fs_u2i     = (unsigned short*)take((size_t)NU_ * HD_ * 2);
  unsigned short* fs_i2u     = (unsigned short*)take((size_t)NI_ * HD_ * 2);
  unsigned short* Wt_src_u2i = (unsigned short*)take((size_t)HD_ * F_ * 2);
  unsigned short* Wt_res_u2i = (unsigned short*)take((size_t)HD_ * F_ * 2);
  unsigned short* Wt_src_i2u = (unsigned short*)take((size_t)HD_ * F_ * 2);
  unsigned short* Wt_res_i2u = (unsigned short*)take((size_t)HD_ * F_ * 2);
  float* wl_u2i = (float*)take(2048 * 4);
  float* wr_u2i = (float*)take(2048 * 4);
  float* wl_i2u = (float*)take(2048 * 4);
  float* wr_i2u = (float*)take(2048 * 4);
  float* el_u2i = (float*)take((size_t)NU_ * 8 * 4);
  float* er_u2i = (float*)take((size_t)NI_ * 8 * 4);
  float* el_i2u = (float*)take((size_t)NI_ * 8 * 4);
  float* er_i2u = (float*)take((size_t)NU_ * 8 * 4);
  // ---- zero block (contiguous): deg_all, mkey_u2i, s_u2i, mkey_i2u, s_i2u ----
  int*      deg_all  = (int*)take((size_t)(NI_ + NU_) * 4);
  unsigned* mkey_u2i = (unsigned*)take((size_t)NI_ * 8 * 4);
  float*    s_u2i    = (float*)take((size_t)NI_ * 8 * 4);
  unsigned* mkey_i2u = (unsigned*)take((size_t)NU_ * 8 * 4);
  float*    s_i2u    = (float*)take((size_t)NU_ * 8 * 4);
  size_t zero_bytes = (size_t)((char*)s_i2u + (size_t)NU_ * 8 * 4 - (char*)deg_all);
  // ---- end zero block ----
  int* rowstart_all = (int*)take((size_t)(SCAN_N + 1) * 4);
  int* cursor_all   = (int*)take((size_t)SCAN_N * 4);
  int* bsum         = (int*)take((size_t)128 * 4);
  int* eids_all     = (int*)take((size_t)2 * NE_ * 4);
  float* val_u2i = (float*)take((size_t)NE_ * 8 * 4);
  float* val_i2u = (float*)take((size_t)NE_ * 8 * 4);

  hipMemsetAsync(deg_all, 0, zero_bytes, stream);

  // weights: transpose+bf16 convert, and attention-vector folds
  wconv_kernel<<<512, 256, 0, stream>>>(W_src_u2i, Wt_src_u2i);
  wconv_kernel<<<512, 256, 0, stream>>>(W_res_u2i, Wt_res_u2i);
  wconv_kernel<<<512, 256, 0, stream>>>(W_src_i2u, Wt_src_i2u);
  wconv_kernel<<<512, 256, 0, stream>>>(W_res_i2u, Wt_res_i2u);
  fold_kernel<<<8, 256, 0, stream>>>(W_src_u2i, al_u2i, wl_u2i);
  fold_kernel<<<8, 256, 0, stream>>>(W_dst_u2i, ar_u2i, wr_u2i);
  fold_kernel<<<8, 256, 0, stream>>>(W_src_i2u, al_i2u, wl_i2u);
  fold_kernel<<<8, 256, 0, stream>>>(W_dst_i2u, ar_i2u, wr_i2u);

  // el/er: users need (el_u2i, er_i2u), items need (el_i2u, er_u2i)
  attvec_kernel<<<(NU_ + 3) / 4, 256, 0, stream>>>(h_user, wl_u2i, wr_i2u, el_u2i, er_i2u, NU_);
  attvec_kernel<<<(NI_ + 3) / 4, 256, 0, stream>>>(h_item, wl_i2u, wr_u2i, el_i2u, er_u2i, NI_);

  // GEMMs: fs -> ws (bf16); res+bias -> d_out (f32, output initializer)
  constexpr int MT_U = (NU_ + 127) / 128;  // 782
  constexpr int MT_I = (NI_ + 127) / 128;  // 391
  gemm_kernel<0><<<MT_U * 4, 256, 0, stream>>>(h_user, Wt_src_u2i, fs_u2i, nullptr, NU_);
  gemm_kernel<0><<<MT_I * 4, 256, 0, stream>>>(h_item, Wt_src_i2u, fs_i2u, nullptr, NI_);
  gemm_kernel<1><<<MT_I * 4, 256, 0, stream>>>(h_item, Wt_res_u2i, out_item, bias_u2i, NI_);
  gemm_kernel<1><<<MT_U * 4, 256, 0, stream>>>(h_user, Wt_res_i2u, out_user, bias_i2u, NU_);

  // edge softmax: pass 1 (max + degree histogram)
  constexpr int EB = (NE_ + 255) / 256;
  edge_max_kernel<<<EB, 256, 0, stream>>>(src_u2i, dst_u2i, el_u2i, er_u2i, val_u2i,
                                          mkey_u2i, deg_all, NE_);
  edge_max_kernel<<<EB, 256, 0, stream>>>(src_i2u, dst_i2u, el_i2u, er_i2u, val_i2u,
                                          mkey_i2u, deg_all + NI_, NE_);
  // CSR scan: two-level (items segment first, then users)
  scan_reduce_kernel<<<SCAN_NB, 256, 0, stream>>>(deg_all, bsum);
  scan_part_kernel<<<1, 128, 0, stream>>>(bsum, SCAN_NB);
  scan_apply_kernel<<<SCAN_NB, 256, 0, stream>>>(deg_all, bsum, rowstart_all, cursor_all);
  // pass 2: exp + segment-sum + CSR binning
  edge_exp_kernel<<<EB, 256, 0, stream>>>(dst_u2i, val_u2i, mkey_u2i, s_u2i,
                                          cursor_all, eids_all, NE_);
  edge_exp_kernel<<<EB, 256, 0, stream>>>(dst_i2u, val_i2u, mkey_i2u, s_i2u,
                                          cursor_all + NI_, eids_all, NE_);
  // pass 3: wave-per-node gather-accumulate (no atomics)
  accum_kernel<<<(NI_ + 3) / 4, 256, 0, stream>>>(rowstart_all, eids_all, src_u2i,
                                                  val_u2i, s_u2i, fs_u2i, out_item, NI_);
  accum_kernel<<<(NU_ + 3) / 4, 256, 0, stream>>>(rowstart_all + NI_, eids_all, src_i2u,
                                                  val_i2u, s_i2u, fs_i2u, out_user, NU_);
}

// Round 4
// 1043.196 us; speedup vs baseline: 8.8826x; 1.3426x over previous
//
#include <hip/hip_runtime.h>
#include <cstdint>
#include <cstddef>

// Problem constants
#define NU_ 100000
#define NI_ 50000
#define F_ 256
#define H_ 8
#define HD_ 512
#define NE_ 300000
#define SLOPE_ 0.2f

#define SCAN_N (NI_ + NU_)
#define SCAN_CHUNK 2048
#define SCAN_NB ((SCAN_N + SCAN_CHUNK - 1) / SCAN_CHUNK)  // 74

typedef float f32x4 __attribute__((ext_vector_type(4)));
typedef __bf16 bf16x8 __attribute__((ext_vector_type(8)));
typedef unsigned short u16x8 __attribute__((ext_vector_type(8)));
typedef unsigned short u16x4 __attribute__((ext_vector_type(4)));

static __device__ __forceinline__ unsigned short f2bf_bits(float f) {
  unsigned u = __float_as_uint(f);
  u += 0x7fffu + ((u >> 16) & 1u);   // RNE
  return (unsigned short)(u >> 16);
}
static __device__ __forceinline__ float bf2f(unsigned short b) {
  return __uint_as_float(((unsigned)b) << 16);
}

// ---------------- all 4 W [256][512] f32 -> Wt [512][256] bf16 (concatenated) --------
__global__ __launch_bounds__(256) void wconv_all_kernel(const float* __restrict__ W0,
                                                        const float* __restrict__ W1,
                                                        const float* __restrict__ W2,
                                                        const float* __restrict__ W3,
                                                        unsigned short* __restrict__ Wt) {
  int idx = blockIdx.x * 256 + threadIdx.x;   // 4*131072
  int m = idx >> 17;
  int r = idx & 131071;
  const float* W = (m == 0) ? W0 : (m == 1) ? W1 : (m == 2) ? W2 : W3;
  int f = r & 255, c = r >> 8;
  Wt[idx] = f2bf_bits(W[(size_t)f * HD_ + c]);
}

// ---------------- 4 folds: out[m][h][f] = sum_d W_m[f][h*64+d]*av_m[h*64+d] ----------
__global__ __launch_bounds__(256) void fold_all_kernel(const float* __restrict__ W0,
                                                       const float* __restrict__ W1,
                                                       const float* __restrict__ W2,
                                                       const float* __restrict__ W3,
                                                       const float* __restrict__ a0,
                                                       const float* __restrict__ a1,
                                                       const float* __restrict__ a2,
                                                       const float* __restrict__ a3,
                                                       float* __restrict__ outf) {
  int m = blockIdx.x >> 3;                     // 32 blocks, 8 per matrix
  int idx = (blockIdx.x & 7) * 256 + threadIdx.x;  // 0..2047
  const float* W = (m == 0) ? W0 : (m == 1) ? W1 : (m == 2) ? W2 : W3;
  const float* av = (m == 0) ? a0 : (m == 1) ? a1 : (m == 2) ? a2 : a3;
  int f = idx & 255, hh = idx >> 8;
  float acc = 0.f;
#pragma unroll 8
  for (int d = 0; d < 64; ++d) acc += W[(size_t)f * HD_ + hh * 64 + d] * av[hh * 64 + d];
  outf[m * 2048 + hh * 256 + f] = acc;
}

// ---------------- per node logits: users rows [0,NU), items rows [NU,NU+NI) ----------
// wf layout: [0]=wl_u2i [1]=wr_u2i [2]=wl_i2u [3]=wr_i2u (each [8][256])
__global__ __launch_bounds__(256) void attvec_kernel(const float* __restrict__ h_user,
                                                     const float* __restrict__ h_item,
                                                     const float* __restrict__ wf,
                                                     float* __restrict__ el_u2i,
                                                     float* __restrict__ er_i2u,
                                                     float* __restrict__ el_i2u,
                                                     float* __restrict__ er_u2i) {
  __shared__ float sA[2048], sB[2048];
  int base = blockIdx.x * 4;                   // NU_ % 4 == 0 -> block never straddles
  bool user = base < NU_;
  const float* h  = user ? h_user : h_item;
  const float* fA = user ? (wf + 0 * 2048) : (wf + 2 * 2048);  // wl_u2i / wl_i2u
  const float* fB = user ? (wf + 3 * 2048) : (wf + 1 * 2048);  // wr_i2u / wr_u2i
  float* oA = user ? el_u2i : el_i2u;
  float* oB = user ? er_i2u : er_u2i;
  int row0 = user ? base : base - NU_;
  for (int i = threadIdx.x; i < 2048; i += 256) { sA[i] = fA[i]; sB[i] = fB[i]; }
  __syncthreads();
  int wave = threadIdx.x >> 6, lane = threadIdx.x & 63;
  int row = row0 + wave;
  float aA[8] = {}, aB[8] = {};
#pragma unroll
  for (int j = 0; j < 4; ++j) {
    int f = lane + j * 64;
    float x = h[(size_t)row * F_ + f];
#pragma unroll
    for (int t = 0; t < 8; ++t) { aA[t] += x * sA[t * 256 + f]; aB[t] += x * sB[t * 256 + f]; }
  }
#pragma unroll
  for (int t = 0; t < 8; ++t) {
    for (int o = 32; o > 0; o >>= 1) {
      aA[t] += __shfl_down(aA[t], o);
      aB[t] += __shfl_down(aB[t], o);
    }
  }
  if (lane == 0) {
#pragma unroll
    for (int t = 0; t < 8; ++t) {
      oA[(size_t)row * 8 + t] = aA[t];
      oB[(size_t)row * 8 + t] = aB[t];
    }
  }
}

// ---------------- dual GEMM: C1 = A@B1 -> bf16 fs;  C2 = A@B2 + bias -> f32 out ------
__global__ __launch_bounds__(256) void gemm2_kernel(const float* __restrict__ A,
                                                    const unsigned short* __restrict__ B1t,
                                                    const unsigned short* __restrict__ B2t,
                                                    unsigned short* __restrict__ fs,
                                                    float* __restrict__ outp,
                                                    const float* __restrict__ bias, int M) {
  __shared__ unsigned short Alds[128][40];
  __shared__ unsigned short B1lds[128][40];
  __shared__ unsigned short B2lds[128][40];
  int tid = threadIdx.x;
  int lane = tid & 63;
  int wave = tid >> 6;
  int wm = wave >> 1, wn = wave & 1;
  int bid = blockIdx.x;
  int mt = bid >> 2, nt = bid & 3;
  int bm = mt * 128, bn = nt * 128;
  f32x4 acc1[4][4] = {};
  f32x4 acc2[4][4] = {};
  int lr = lane & 15;
  int kk = (lane >> 4) * 8;

  for (int k0 = 0; k0 < 256; k0 += 32) {
#pragma unroll
    for (int it = 0; it < 4; ++it) {
      int idx = tid + it * 256;
      int row = idx >> 3;
      int c4 = (idx & 7) << 2;
      f32x4 v = {};
      int gr = bm + row;
      if (gr < M) v = *(const f32x4*)&A[(size_t)gr * 256 + k0 + c4];
      u16x4 b;
      b.x = f2bf_bits(v.x); b.y = f2bf_bits(v.y); b.z = f2bf_bits(v.z); b.w = f2bf_bits(v.w);
      *(u16x4*)&Alds[row][c4] = b;
    }
#pragma unroll
    for (int it = 0; it < 2; ++it) {
      int idx = tid + it * 256;
      int row = idx >> 2;
      int c8 = (idx & 3) << 3;
      *(u16x8*)&B1lds[row][c8] = *(const u16x8*)&B1t[(size_t)(bn + row) * 256 + k0 + c8];
      *(u16x8*)&B2lds[row][c8] = *(const u16x8*)&B2t[(size_t)(bn + row) * 256 + k0 + c8];
    }
    __syncthreads();
    bf16x8 af[4], b1[4], b2[4];
#pragma unroll
    for (int m = 0; m < 4; ++m)
      af[m] = __builtin_bit_cast(bf16x8, *(const u16x8*)&Alds[wm * 64 + m * 16 + lr][kk]);
#pragma unroll
    for (int n = 0; n < 4; ++n) {
      b1[n] = __builtin_bit_cast(bf16x8, *(const u16x8*)&B1lds[wn * 64 + n * 16 + lr][kk]);
      b2[n] = __builtin_bit_cast(bf16x8, *(const u16x8*)&B2lds[wn * 64 + n * 16 + lr][kk]);
    }
#pragma unroll
    for (int m = 0; m < 4; ++m)
#pragma unroll
      for (int n = 0; n < 4; ++n) {
        acc1[m][n] = __builtin_amdgcn_mfma_f32_16x16x32_bf16(af[m], b1[n], acc1[m][n], 0, 0, 0);
        acc2[m][n] = __builtin_amdgcn_mfma_f32_16x16x32_bf16(af[m], b2[n], acc2[m][n], 0, 0, 0);
      }
    __syncthreads();
  }

  int rg = (lane >> 4) * 4;
#pragma unroll
  for (int m = 0; m < 4; ++m) {
#pragma unroll
    for (int r = 0; r < 4; ++r) {
      int row = bm + wm * 64 + m * 16 + rg + r;
      if (row >= M) continue;
#pragma unroll
      for (int n = 0; n < 4; ++n) {
        int col = bn + wn * 64 + n * 16 + lr;
        fs[(size_t)row * HD_ + col] = f2bf_bits(acc1[m][n][r]);
        outp[(size_t)row * HD_ + col] = acc2[m][n][r] + bias[col];
      }
    }
  }
}

// ---------------- degree histogram over both directions ----------------
__global__ __launch_bounds__(256) void hist_kernel(const int* __restrict__ dst_u2i,
                                                   const int* __restrict__ dst_i2u,
                                                   int* __restrict__ deg) {
  int e = blockIdx.x * 256 + threadIdx.x;
  if (e < NE_) atomicAdd(&deg[dst_u2i[e]], 1);
  else if (e < 2 * NE_) atomicAdd(&deg[NI_ + dst_i2u[e - NE_]], 1);
}

// ---------------- two-level scan over deg ----------------
__global__ __launch_bounds__(256) void scan_reduce_kernel(const int* __restrict__ deg,
                                                          int* __restrict__ bsum) {
  __shared__ int lds[256];
  int tid = threadIdx.x;
  int base = blockIdx.x * SCAN_CHUNK + tid * 8;
  int sum = 0;
#pragma unroll
  for (int j = 0; j < 8; ++j) sum += (base + j < SCAN_N) ? deg[base + j] : 0;
  lds[tid] = sum;
  __syncthreads();
  for (int o = 128; o > 0; o >>= 1) {
    if (tid < o) lds[tid] += lds[tid + o];
    __syncthreads();
  }
  if (tid == 0) bsum[blockIdx.x] = lds[0];
}

__global__ __launch_bounds__(128) void scan_part_kernel(int* __restrict__ bsum, int nb) {
  __shared__ int lds[128];
  int tid = threadIdx.x;
  int v = (tid < nb) ? bsum[tid] : 0;
  lds[tid] = v;
  __syncthreads();
  for (int o = 1; o < 128; o <<= 1) {
    int t = (tid >= o) ? lds[tid - o] : 0;
    __syncthreads();
    lds[tid] += t;
    __syncthreads();
  }
  if (tid < nb) bsum[tid] = lds[tid] - v;
}

__global__ __launch_bounds__(256) void scan_apply_kernel(const int* __restrict__ deg,
                                                         const int* __restrict__ bsum,
                                                         int* __restrict__ rowstart,
                                                         int* __restrict__ cursor) {
  __shared__ int lds[256];
  int tid = threadIdx.x;
  int base = blockIdx.x * SCAN_CHUNK + tid * 8;
  int v[8];
  int sum = 0;
#pragma unroll
  for (int j = 0; j < 8; ++j) {
    v[j] = (base + j < SCAN_N) ? deg[base + j] : 0;
    sum += v[j];
  }
  lds[tid] = sum;
  __syncthreads();
  for (int o = 1; o < 256; o <<= 1) {
    int t = (tid >= o) ? lds[tid - o] : 0;
    __syncthreads();
    lds[tid] += t;
    __syncthreads();
  }
  int run = bsum[blockIdx.x] + lds[tid] - sum;
#pragma unroll
  for (int j = 0; j < 8; ++j) {
    if (base + j < SCAN_N) { rowstart[base + j] = run; cursor[base + j] = run; }
    run += v[j];
  }
  if (blockIdx.x == 0 && tid == 0) rowstart[SCAN_N] = 2 * NE_;
}

// ---------------- bin: scatter source node ids into CSR slots ----------------
__global__ __launch_bounds__(256) void bin_kernel(const int* __restrict__ src_u2i,
                                                  const int* __restrict__ dst_u2i,
                                                  const int* __restrict__ src_i2u,
                                                  const int* __restrict__ dst_i2u,
                                                  int* __restrict__ cursor,
                                                  int* __restrict__ ssrc) {
  int e = blockIdx.x * 256 + threadIdx.x;
  int de, se;
  if (e < NE_) { de = dst_u2i[e]; se = src_u2i[e]; }
  else if (e < 2 * NE_) { de = NI_ + dst_i2u[e - NE_]; se = src_i2u[e - NE_]; }
  else return;
  int pos = atomicAdd(&cursor[de], 1);
  ssrc[pos] = se;
}

// ---------------- fused accum: online softmax + weighted fs gather + residual RMW ----
__global__ __launch_bounds__(256) void accum_kernel(const int* __restrict__ rowstart,
                                                    const int* __restrict__ ssrc,
                                                    const float* __restrict__ el_u2i,
                                                    const float* __restrict__ el_i2u,
                                                    const float* __restrict__ er_u2i,
                                                    const float* __restrict__ er_i2u,
                                                    const unsigned short* __restrict__ fs_u2i,
                                                    const unsigned short* __restrict__ fs_i2u,
                                                    float* __restrict__ out_item,
                                                    float* __restrict__ out_user) {
  int n = blockIdx.x * 4 + (threadIdx.x >> 6);
  if (n >= SCAN_N) return;
  int r0 = rowstart[n], r1 = rowstart[n + 1];
  if (r0 == r1) return;   // no edges: out keeps residual+bias
  int lane = threadIdx.x & 63;
  bool item = n < NI_;
  int ln = item ? n : n - NI_;
  const float* el = item ? el_u2i : el_i2u;
  const float* er = item ? er_u2i : er_i2u;
  const unsigned short* fs = item ? fs_u2i : fs_i2u;
  float* out = (item ? out_item + (size_t)ln * HD_ : out_user + (size_t)ln * HD_);
  int hh = lane >> 3;
  float erh = er[(size_t)ln * 8 + hh];
  float m = -3.0e38f, s = 0.f;
  float acc[8] = {};
  for (int k = r0; k < r1; ++k) {
    int se = ssrc[k];
    float e = el[(size_t)se * 8 + hh] + erh;
    e = e > 0.f ? e : SLOPE_ * e;
    if (e > m) {
      float r = __expf(m - e);
      s *= r;
#pragma unroll
      for (int j = 0; j < 8; ++j) acc[j] *= r;
      m = e;
    }
    float x = __expf(e - m);
    s += x;
    u16x8 v = *(const u16x8*)&fs[(size_t)se * HD_ + lane * 8];
#pragma unroll
    for (int j = 0; j < 8; ++j) acc[j] += x * bf2f((unsigned short)v[j]);
  }
  float inv = 1.f / s;
  float* op = out + lane * 8;
  f32x4 o0 = *(f32x4*)op, o1 = *(f32x4*)(op + 4);
#pragma unroll
  for (int j = 0; j < 4; ++j) { o0[j] += acc[j] * inv; o1[j] += acc[4 + j] * inv; }
  *(f32x4*)op = o0;
  *(f32x4*)(op + 4) = o1;
}

// =====================================================================================
extern "C" void kernel_launch(void* const* d_in, const int* in_sizes, int n_in,
                              void* d_out, int out_size, void* d_ws, size_t ws_size,
                              hipStream_t stream) {
  const float* h_user    = (const float*)d_in[0];
  const float* h_item    = (const float*)d_in[1];
  const int*   src_u2i   = (const int*)d_in[2];
  const int*   dst_u2i   = (const int*)d_in[3];
  const int*   src_i2u   = (const int*)d_in[4];
  const int*   dst_i2u   = (const int*)d_in[5];
  const float* W_src_u2i = (const float*)d_in[6];
  const float* W_dst_u2i = (const float*)d_in[7];
  const float* al_u2i    = (const float*)d_in[8];
  const float* ar_u2i    = (const float*)d_in[9];
  const float* bias_u2i  = (const float*)d_in[10];
  const float* W_res_u2i = (const float*)d_in[11];
  const float* W_src_i2u = (const float*)d_in[12];
  const float* W_dst_i2u = (const float*)d_in[13];
  const float* al_i2u    = (const float*)d_in[14];
  const float* ar_i2u    = (const float*)d_in[15];
  const float* bias_i2u  = (const float*)d_in[16];
  const float* W_res_i2u = (const float*)d_in[17];

  float* out_user = (float*)d_out;                       // [NU,512]
  float* out_item = (float*)d_out + (size_t)NU_ * HD_;   // [NI,512]

  char* ws = (char*)d_ws;
  size_t off = 0;
  auto take = [&](size_t bytes) -> char* {
    char* p = ws + off;
    off += (bytes + 255) & ~(size_t)255;
    return p;
  };
  unsigned short* fs_u2i = (unsigned short*)take((size_t)NU_ * HD_ * 2);
  unsigned short* fs_i2u = (unsigned short*)take((size_t)NI_ * HD_ * 2);
  // Wt_all: [0]=src_u2i [1]=res_u2i [2]=src_i2u [3]=res_i2u, each [512][256] bf16
  unsigned short* Wt_all = (unsigned short*)take((size_t)4 * HD_ * F_ * 2);
  unsigned short* Wt_src_u2i = Wt_all;
  unsigned short* Wt_res_u2i = Wt_all + 1 * HD_ * F_;
  unsigned short* Wt_src_i2u = Wt_all + 2 * HD_ * F_;
  unsigned short* Wt_res_i2u = Wt_all + 3 * HD_ * F_;
  // wf: [0]=wl_u2i [1]=wr_u2i [2]=wl_i2u [3]=wr_i2u
  float* wf = (float*)take((size_t)4 * 2048 * 4);
  float* el_u2i = (float*)take((size_t)NU_ * 8 * 4);
  float* er_i2u = (float*)take((size_t)NU_ * 8 * 4);
  float* el_i2u = (float*)take((size_t)NI_ * 8 * 4);
  float* er_u2i = (float*)take((size_t)NI_ * 8 * 4);
  int* deg_all      = (int*)take((size_t)SCAN_N * 4);        // zeroed
  int* rowstart_all = (int*)take((size_t)(SCAN_N + 1) * 4);
  int* cursor_all   = (int*)take((size_t)SCAN_N * 4);
  int* bsum         = (int*)take((size_t)128 * 4);
  int* ssrc         = (int*)take((size_t)2 * NE_ * 4);

  hipMemsetAsync(deg_all, 0, (size_t)SCAN_N * 4, stream);

  // weights: transpose+convert (1 kernel), attention folds (1 kernel)
  wconv_all_kernel<<<2048, 256, 0, stream>>>(W_src_u2i, W_res_u2i, W_src_i2u, W_res_i2u, Wt_all);
  fold_all_kernel<<<32, 256, 0, stream>>>(W_src_u2i, W_dst_u2i, W_src_i2u, W_dst_i2u,
                                          al_u2i, ar_u2i, al_i2u, ar_i2u, wf);

  // per-node logits (users + items in one grid)
  attvec_kernel<<<SCAN_N / 4, 256, 0, stream>>>(h_user, h_item, wf,
                                                el_u2i, er_i2u, el_i2u, er_u2i);

  // CSR build: histogram -> scan -> bin
  constexpr int EB2 = (2 * NE_ + 255) / 256;
  hist_kernel<<<EB2, 256, 0, stream>>>(dst_u2i, dst_i2u, deg_all);
  scan_reduce_kernel<<<SCAN_NB, 256, 0, stream>>>(deg_all, bsum);
  scan_part_kernel<<<1, 128, 0, stream>>>(bsum, SCAN_NB);
  scan_apply_kernel<<<SCAN_NB, 256, 0, stream>>>(deg_all, bsum, rowstart_all, cursor_all);
  bin_kernel<<<EB2, 256, 0, stream>>>(src_u2i, dst_u2i, src_i2u, dst_i2u, cursor_all, ssrc);

  // dual GEMMs: fs (bf16, ws) + residual+bias (f32, d_out)
  constexpr int MT_U = (NU_ + 127) / 128;  // 782
  constexpr int MT_I = (NI_ + 127) / 128;  // 391
  gemm2_kernel<<<MT_U * 4, 256, 0, stream>>>(h_user, Wt_src_u2i, Wt_res_i2u,
                                             fs_u2i, out_user, bias_i2u, NU_);
  gemm2_kernel<<<MT_I * 4, 256, 0, stream>>>(h_item, Wt_src_i2u, Wt_res_u2i,
                                             fs_i2u, out_item, bias_u2i, NI_);

  // fused online-softmax gather-accumulate (items + users in one grid)
  accum_kernel<<<SCAN_N / 4, 256, 0, stream>>>(rowstart_all, ssrc,
                                               el_u2i, el_i2u, er_u2i, er_i2u,
                                               fs_u2i, fs_i2u, out_item, out_user);
}

// Round 5
// 666.487 us; speedup vs baseline: 13.9031x; 1.5652x over previous
//
#include <hip/hip_runtime.h>
#include <cstdint>
#include <cstddef>

// Problem constants
#define NU_ 100000
#define NI_ 50000
#define F_ 256
#define H_ 8
#define HD_ 512
#define NE_ 300000
#define SLOPE_ 0.2f

#define MPAD_U 100096   // NU_ rounded up to 128
#define MPAD_I 50048    // NI_ rounded up to 128

#define SCAN_N (NI_ + NU_)
#define SCAN_CHUNK 2048
#define SCAN_NB ((SCAN_N + SCAN_CHUNK - 1) / SCAN_CHUNK)  // 74

typedef float f32x4 __attribute__((ext_vector_type(4)));
typedef __bf16 bf16x8 __attribute__((ext_vector_type(8)));
typedef unsigned short u16x8 __attribute__((ext_vector_type(8)));
typedef unsigned short u16x4 __attribute__((ext_vector_type(4)));

static __device__ __forceinline__ unsigned short f2bf_bits(float f) {
  unsigned u = __float_as_uint(f);
  u += 0x7fffu + ((u >> 16) & 1u);   // RNE
  return (unsigned short)(u >> 16);
}
static __device__ __forceinline__ float bf2f(unsigned short b) {
  return __uint_as_float(((unsigned)b) << 16);
}

// async global->LDS, 16B per lane; dest must be wave-uniform base + lane*16
#define GLL16(g, l)                                                        \
  __builtin_amdgcn_global_load_lds(                                        \
      (const __attribute__((address_space(1))) void*)(g),                  \
      (__attribute__((address_space(3))) void*)(l), 16, 0, 0)

// ---------------- all 4 W [256][512] f32 -> Wt [512][256] bf16 (concatenated) --------
__global__ __launch_bounds__(256) void wconv_all_kernel(const float* __restrict__ W0,
                                                        const float* __restrict__ W1,
                                                        const float* __restrict__ W2,
                                                        const float* __restrict__ W3,
                                                        unsigned short* __restrict__ Wt) {
  int idx = blockIdx.x * 256 + threadIdx.x;   // 4*131072
  int m = idx >> 17;
  int r = idx & 131071;
  const float* W = (m == 0) ? W0 : (m == 1) ? W1 : (m == 2) ? W2 : W3;
  int f = r & 255, c = r >> 8;
  Wt[idx] = f2bf_bits(W[(size_t)f * HD_ + c]);
}

// ---------------- 4 folds: out[m][h][f] = sum_d W_m[f][h*64+d]*av_m[h*64+d] ----------
__global__ __launch_bounds__(256) void fold_all_kernel(const float* __restrict__ W0,
                                                       const float* __restrict__ W1,
                                                       const float* __restrict__ W2,
                                                       const float* __restrict__ W3,
                                                       const float* __restrict__ a0,
                                                       const float* __restrict__ a1,
                                                       const float* __restrict__ a2,
                                                       const float* __restrict__ a3,
                                                       float* __restrict__ outf) {
  int m = blockIdx.x >> 3;                     // 32 blocks, 8 per matrix
  int idx = (blockIdx.x & 7) * 256 + threadIdx.x;  // 0..2047
  const float* W = (m == 0) ? W0 : (m == 1) ? W1 : (m == 2) ? W2 : W3;
  const float* av = (m == 0) ? a0 : (m == 1) ? a1 : (m == 2) ? a2 : a3;
  int f = idx & 255, hh = idx >> 8;
  float acc = 0.f;
#pragma unroll 8
  for (int d = 0; d < 64; ++d) acc += W[(size_t)f * HD_ + hh * 64 + d] * av[hh * 64 + d];
  outf[m * 2048 + hh * 256 + f] = acc;
}

// ---------------- per node logits + bf16 copy of h ----------------
// users rows [0,NU), items rows [NU,NU+NI); wf: [0]=wl_u2i [1]=wr_u2i [2]=wl_i2u [3]=wr_i2u
__global__ __launch_bounds__(256) void attvec_kernel(const float* __restrict__ h_user,
                                                     const float* __restrict__ h_item,
                                                     const float* __restrict__ wf,
                                                     float* __restrict__ el_u2i,
                                                     float* __restrict__ er_i2u,
                                                     float* __restrict__ el_i2u,
                                                     float* __restrict__ er_u2i,
                                                     unsigned short* __restrict__ hb_user,
                                                     unsigned short* __restrict__ hb_item) {
  __shared__ float sA[2048], sB[2048];
  int base = blockIdx.x * 4;                   // NU_ % 4 == 0 -> block never straddles
  bool user = base < NU_;
  const float* h  = user ? h_user : h_item;
  const float* fA = user ? (wf + 0 * 2048) : (wf + 2 * 2048);  // wl_u2i / wl_i2u
  const float* fB = user ? (wf + 3 * 2048) : (wf + 1 * 2048);  // wr_i2u / wr_u2i
  float* oA = user ? el_u2i : el_i2u;
  float* oB = user ? er_i2u : er_u2i;
  unsigned short* hb = user ? hb_user : hb_item;
  int row0 = user ? base : base - NU_;
  for (int i = threadIdx.x; i < 2048; i += 256) { sA[i] = fA[i]; sB[i] = fB[i]; }
  __syncthreads();
  int wave = threadIdx.x >> 6, lane = threadIdx.x & 63;
  int row = row0 + wave;
  // lane covers cols 4*lane .. 4*lane+3
  f32x4 v = *(const f32x4*)&h[(size_t)row * F_ + 4 * lane];
  u16x4 bv;
  bv.x = f2bf_bits(v.x); bv.y = f2bf_bits(v.y); bv.z = f2bf_bits(v.z); bv.w = f2bf_bits(v.w);
  *(u16x4*)&hb[(size_t)row * F_ + 4 * lane] = bv;
  float aA[8], aB[8];
#pragma unroll
  for (int t = 0; t < 8; ++t) {
    f32x4 wA = *(const f32x4*)&sA[t * 256 + 4 * lane];
    f32x4 wB = *(const f32x4*)&sB[t * 256 + 4 * lane];
    aA[t] = v.x * wA.x + v.y * wA.y + v.z * wA.z + v.w * wA.w;
    aB[t] = v.x * wB.x + v.y * wB.y + v.z * wB.z + v.w * wB.w;
  }
#pragma unroll
  for (int t = 0; t < 8; ++t) {
    for (int o = 32; o > 0; o >>= 1) {
      aA[t] += __shfl_down(aA[t], o);
      aB[t] += __shfl_down(aB[t], o);
    }
  }
  if (lane == 0) {
#pragma unroll
    for (int t = 0; t < 8; ++t) {
      oA[(size_t)row * 8 + t] = aA[t];
      oB[(size_t)row * 8 + t] = aB[t];
    }
  }
}

// ---------------- dual GEMM (bf16 A, global_load_lds staging, 2-phase prefetch) ------
// C1 = A@B1 -> bf16 fs;  C2 = A@B2 + bias -> f32 out.  A is padded to 128-row multiple.
__global__ __launch_bounds__(256) void gemm2_kernel(const unsigned short* __restrict__ Ab,
                                                    const unsigned short* __restrict__ B1t,
                                                    const unsigned short* __restrict__ B2t,
                                                    unsigned short* __restrict__ fs,
                                                    float* __restrict__ outp,
                                                    const float* __restrict__ bias, int M) {
  // [buf][mat][row][k] : 2 * 3 * 128 * 32 u16 = 48 KB
  __shared__ unsigned short lds[2][3][128][32];
  int tid = threadIdx.x;
  int lane = tid & 63;
  int wave = tid >> 6;
  int wm = wave >> 1, wn = wave & 1;
  int bid = blockIdx.x;
  int mt = bid >> 2, nt = bid & 3;
  int bm = mt * 128, bn = nt * 128;
  f32x4 acc1[4][4] = {};
  f32x4 acc2[4][4] = {};
  int lr = lane & 15;
  int kk = (lane >> 4) * 8;

  // staging geometry: 512 chunks of 16B per matrix tile; idx = tid + it*256
  int r0 = tid >> 2;            // it=0 rows 0..63
  int c0 = (tid & 3) << 3;      // 8 bf16 = 16 B
  const unsigned short* gA  = &Ab [(size_t)(bm + r0) * 256 + c0];
  const unsigned short* gB1 = &B1t[(size_t)(bn + r0) * 256 + c0];
  const unsigned short* gB2 = &B2t[(size_t)(bn + r0) * 256 + c0];

#define STAGE(buf, t)                                                       \
  do {                                                                      \
    int k0_ = (t) * 32;                                                     \
    GLL16(gA  + k0_,          &lds[buf][0][r0][c0]);                        \
    GLL16(gA  + k0_ + 64*256, &lds[buf][0][r0 + 64][c0]);                   \
    GLL16(gB1 + k0_,          &lds[buf][1][r0][c0]);                        \
    GLL16(gB1 + k0_ + 64*256, &lds[buf][1][r0 + 64][c0]);                   \
    GLL16(gB2 + k0_,          &lds[buf][2][r0][c0]);                        \
    GLL16(gB2 + k0_ + 64*256, &lds[buf][2][r0 + 64][c0]);                   \
  } while (0)

  STAGE(0, 0);
  __syncthreads();            // implicit vmcnt(0): buffer 0 ready
  int cur = 0;
#pragma unroll
  for (int t = 0; t < 8; ++t) {
    if (t < 7) STAGE(cur ^ 1, t + 1);   // prefetch next tile (stays in flight)
    bf16x8 af[4], b1[4], b2[4];
#pragma unroll
    for (int m = 0; m < 4; ++m)
      af[m] = __builtin_bit_cast(bf16x8, *(const u16x8*)&lds[cur][0][wm * 64 + m * 16 + lr][kk]);
#pragma unroll
    for (int n = 0; n < 4; ++n) {
      b1[n] = __builtin_bit_cast(bf16x8, *(const u16x8*)&lds[cur][1][wn * 64 + n * 16 + lr][kk]);
      b2[n] = __builtin_bit_cast(bf16x8, *(const u16x8*)&lds[cur][2][wn * 64 + n * 16 + lr][kk]);
    }
#pragma unroll
    for (int m = 0; m < 4; ++m)
#pragma unroll
      for (int n = 0; n < 4; ++n) {
        acc1[m][n] = __builtin_amdgcn_mfma_f32_16x16x32_bf16(af[m], b1[n], acc1[m][n], 0, 0, 0);
        acc2[m][n] = __builtin_amdgcn_mfma_f32_16x16x32_bf16(af[m], b2[n], acc2[m][n], 0, 0, 0);
      }
    __syncthreads();          // drains vmcnt(0) (next buf ready) + lgkm + barrier
    cur ^= 1;
  }
#undef STAGE

  int rg = (lane >> 4) * 4;
#pragma unroll
  for (int m = 0; m < 4; ++m) {
#pragma unroll
    for (int r = 0; r < 4; ++r) {
      int row = bm + wm * 64 + m * 16 + rg + r;
      if (row >= M) continue;
#pragma unroll
      for (int n = 0; n < 4; ++n) {
        int col = bn + wn * 64 + n * 16 + lr;
        fs[(size_t)row * HD_ + col] = f2bf_bits(acc1[m][n][r]);
        outp[(size_t)row * HD_ + col] = acc2[m][n][r] + bias[col];
      }
    }
  }
}

// ---------------- degree histogram over both directions ----------------
__global__ __launch_bounds__(256) void hist_kernel(const int* __restrict__ dst_u2i,
                                                   const int* __restrict__ dst_i2u,
                                                   int* __restrict__ deg) {
  int e = blockIdx.x * 256 + threadIdx.x;
  if (e < NE_) atomicAdd(&deg[dst_u2i[e]], 1);
  else if (e < 2 * NE_) atomicAdd(&deg[NI_ + dst_i2u[e - NE_]], 1);
}

// ---------------- two-level scan over deg ----------------
__global__ __launch_bounds__(256) void scan_reduce_kernel(const int* __restrict__ deg,
                                                          int* __restrict__ bsum) {
  __shared__ int lds[256];
  int tid = threadIdx.x;
  int base = blockIdx.x * SCAN_CHUNK + tid * 8;
  int sum = 0;
#pragma unroll
  for (int j = 0; j < 8; ++j) sum += (base + j < SCAN_N) ? deg[base + j] : 0;
  lds[tid] = sum;
  __syncthreads();
  for (int o = 128; o > 0; o >>= 1) {
    if (tid < o) lds[tid] += lds[tid + o];
    __syncthreads();
  }
  if (tid == 0) bsum[blockIdx.x] = lds[0];
}

__global__ __launch_bounds__(128) void scan_part_kernel(int* __restrict__ bsum, int nb) {
  __shared__ int lds[128];
  int tid = threadIdx.x;
  int v = (tid < nb) ? bsum[tid] : 0;
  lds[tid] = v;
  __syncthreads();
  for (int o = 1; o < 128; o <<= 1) {
    int t = (tid >= o) ? lds[tid - o] : 0;
    __syncthreads();
    lds[tid] += t;
    __syncthreads();
  }
  if (tid < nb) bsum[tid] = lds[tid] - v;
}

__global__ __launch_bounds__(256) void scan_apply_kernel(const int* __restrict__ deg,
                                                         const int* __restrict__ bsum,
                                                         int* __restrict__ rowstart,
                                                         int* __restrict__ cursor) {
  __shared__ int lds[256];
  int tid = threadIdx.x;
  int base = blockIdx.x * SCAN_CHUNK + tid * 8;
  int v[8];
  int sum = 0;
#pragma unroll
  for (int j = 0; j < 8; ++j) {
    v[j] = (base + j < SCAN_N) ? deg[base + j] : 0;
    sum += v[j];
  }
  lds[tid] = sum;
  __syncthreads();
  for (int o = 1; o < 256; o <<= 1) {
    int t = (tid >= o) ? lds[tid - o] : 0;
    __syncthreads();
    lds[tid] += t;
    __syncthreads();
  }
  int run = bsum[blockIdx.x] + lds[tid] - sum;
#pragma unroll
  for (int j = 0; j < 8; ++j) {
    if (base + j < SCAN_N) { rowstart[base + j] = run; cursor[base + j] = run; }
    run += v[j];
  }
  if (blockIdx.x == 0 && tid == 0) rowstart[SCAN_N] = 2 * NE_;
}

// ---------------- bin: scatter source node ids into CSR slots ----------------
__global__ __launch_bounds__(256) void bin_kernel(const int* __restrict__ src_u2i,
                                                  const int* __restrict__ dst_u2i,
                                                  const int* __restrict__ src_i2u,
                                                  const int* __restrict__ dst_i2u,
                                                  int* __restrict__ cursor,
                                                  int* __restrict__ ssrc) {
  int e = blockIdx.x * 256 + threadIdx.x;
  int de, se;
  if (e < NE_) { de = dst_u2i[e]; se = src_u2i[e]; }
  else if (e < 2 * NE_) { de = NI_ + dst_i2u[e - NE_]; se = src_i2u[e - NE_]; }
  else return;
  int pos = atomicAdd(&cursor[de], 1);
  ssrc[pos] = se;
}

// ---------------- fused accum: online softmax + weighted fs gather + residual RMW ----
__global__ __launch_bounds__(256) void accum_kernel(const int* __restrict__ rowstart,
                                                    const int* __restrict__ ssrc,
                                                    const float* __restrict__ el_u2i,
                                                    const float* __restrict__ el_i2u,
                                                    const float* __restrict__ er_u2i,
                                                    const float* __restrict__ er_i2u,
                                                    const unsigned short* __restrict__ fs_u2i,
                                                    const unsigned short* __restrict__ fs_i2u,
                                                    float* __restrict__ out_item,
                                                    float* __restrict__ out_user) {
  int n = blockIdx.x * 4 + (threadIdx.x >> 6);
  if (n >= SCAN_N) return;
  int r0 = rowstart[n], r1 = rowstart[n + 1];
  if (r0 == r1) return;   // no edges: out keeps residual+bias
  int lane = threadIdx.x & 63;
  bool item = n < NI_;
  int ln = item ? n : n - NI_;
  const float* el = item ? el_u2i : el_i2u;
  const float* er = item ? er_u2i : er_i2u;
  const unsigned short* fs = item ? fs_u2i : fs_i2u;
  float* out = (item ? out_item + (size_t)ln * HD_ : out_user + (size_t)ln * HD_);
  int hh = lane >> 3;
  float erh = er[(size_t)ln * 8 + hh];
  float m = -3.0e38f, s = 0.f;
  float acc[8] = {};
  for (int k = r0; k < r1; ++k) {
    int se = ssrc[k];
    float e = el[(size_t)se * 8 + hh] + erh;
    e = e > 0.f ? e : SLOPE_ * e;
    if (e > m) {
      float r = __expf(m - e);
      s *= r;
#pragma unroll
      for (int j = 0; j < 8; ++j) acc[j] *= r;
      m = e;
    }
    float x = __expf(e - m);
    s += x;
    u16x8 v = *(const u16x8*)&fs[(size_t)se * HD_ + lane * 8];
#pragma unroll
    for (int j = 0; j < 8; ++j) acc[j] += x * bf2f((unsigned short)v[j]);
  }
  float inv = 1.f / s;
  float* op = out + lane * 8;
  f32x4 o0 = *(f32x4*)op, o1 = *(f32x4*)(op + 4);
#pragma unroll
  for (int j = 0; j < 4; ++j) { o0[j] += acc[j] * inv; o1[j] += acc[4 + j] * inv; }
  *(f32x4*)op = o0;
  *(f32x4*)(op + 4) = o1;
}

// =====================================================================================
extern "C" void kernel_launch(void* const* d_in, const int* in_sizes, int n_in,
                              void* d_out, int out_size, void* d_ws, size_t ws_size,
                              hipStream_t stream) {
  const float* h_user    = (const float*)d_in[0];
  const float* h_item    = (const float*)d_in[1];
  const int*   src_u2i   = (const int*)d_in[2];
  const int*   dst_u2i   = (const int*)d_in[3];
  const int*   src_i2u   = (const int*)d_in[4];
  const int*   dst_i2u   = (const int*)d_in[5];
  const float* W_src_u2i = (const float*)d_in[6];
  const float* W_dst_u2i = (const float*)d_in[7];
  const float* al_u2i    = (const float*)d_in[8];
  const float* ar_u2i    = (const float*)d_in[9];
  const float* bias_u2i  = (const float*)d_in[10];
  const float* W_res_u2i = (const float*)d_in[11];
  const float* W_src_i2u = (const float*)d_in[12];
  const float* W_dst_i2u = (const float*)d_in[13];
  const float* al_i2u    = (const float*)d_in[14];
  const float* ar_i2u    = (const float*)d_in[15];
  const float* bias_i2u  = (const float*)d_in[16];
  const float* W_res_i2u = (const float*)d_in[17];

  float* out_user = (float*)d_out;                       // [NU,512]
  float* out_item = (float*)d_out + (size_t)NU_ * HD_;   // [NI,512]

  char* ws = (char*)d_ws;
  size_t off = 0;
  auto take = [&](size_t bytes) -> char* {
    char* p = ws + off;
    off += (bytes + 255) & ~(size_t)255;
    return p;
  };
  unsigned short* fs_u2i = (unsigned short*)take((size_t)NU_ * HD_ * 2);
  unsigned short* fs_i2u = (unsigned short*)take((size_t)NI_ * HD_ * 2);
  unsigned short* hb_user = (unsigned short*)take((size_t)MPAD_U * F_ * 2);
  unsigned short* hb_item = (unsigned short*)take((size_t)MPAD_I * F_ * 2);
  // Wt_all: [0]=src_u2i [1]=res_u2i [2]=src_i2u [3]=res_i2u, each [512][256] bf16
  unsigned short* Wt_all = (unsigned short*)take((size_t)4 * HD_ * F_ * 2);
  unsigned short* Wt_src_u2i = Wt_all;
  unsigned short* Wt_res_u2i = Wt_all + 1 * HD_ * F_;
  unsigned short* Wt_src_i2u = Wt_all + 2 * HD_ * F_;
  unsigned short* Wt_res_i2u = Wt_all + 3 * HD_ * F_;
  // wf: [0]=wl_u2i [1]=wr_u2i [2]=wl_i2u [3]=wr_i2u
  float* wf = (float*)take((size_t)4 * 2048 * 4);
  float* el_u2i = (float*)take((size_t)NU_ * 8 * 4);
  float* er_i2u = (float*)take((size_t)NU_ * 8 * 4);
  float* el_i2u = (float*)take((size_t)NI_ * 8 * 4);
  float* er_u2i = (float*)take((size_t)NI_ * 8 * 4);
  int* deg_all      = (int*)take((size_t)SCAN_N * 4);        // zeroed
  int* rowstart_all = (int*)take((size_t)(SCAN_N + 1) * 4);
  int* cursor_all   = (int*)take((size_t)SCAN_N * 4);
  int* bsum         = (int*)take((size_t)128 * 4);
  int* ssrc         = (int*)take((size_t)2 * NE_ * 4);

  hipMemsetAsync(deg_all, 0, (size_t)SCAN_N * 4, stream);

  // weights: transpose+convert (1 kernel), attention folds (1 kernel)
  wconv_all_kernel<<<2048, 256, 0, stream>>>(W_src_u2i, W_res_u2i, W_src_i2u, W_res_i2u, Wt_all);
  fold_all_kernel<<<32, 256, 0, stream>>>(W_src_u2i, W_dst_u2i, W_src_i2u, W_dst_i2u,
                                          al_u2i, ar_u2i, al_i2u, ar_i2u, wf);

  // per-node logits + bf16 h copy (users + items in one grid)
  attvec_kernel<<<SCAN_N / 4, 256, 0, stream>>>(h_user, h_item, wf,
                                                el_u2i, er_i2u, el_i2u, er_u2i,
                                                hb_user, hb_item);

  // CSR build: histogram -> scan -> bin
  constexpr int EB2 = (2 * NE_ + 255) / 256;
  hist_kernel<<<EB2, 256, 0, stream>>>(dst_u2i, dst_i2u, deg_all);
  scan_reduce_kernel<<<SCAN_NB, 256, 0, stream>>>(deg_all, bsum);
  scan_part_kernel<<<1, 128, 0, stream>>>(bsum, SCAN_NB);
  scan_apply_kernel<<<SCAN_NB, 256, 0, stream>>>(deg_all, bsum, rowstart_all, cursor_all);
  bin_kernel<<<EB2, 256, 0, stream>>>(src_u2i, dst_u2i, src_i2u, dst_i2u, cursor_all, ssrc);

  // dual GEMMs: fs (bf16, ws) + residual+bias (f32, d_out)
  constexpr int MT_U = MPAD_U / 128;  // 782
  constexpr int MT_I = MPAD_I / 128;  // 391
  gemm2_kernel<<<MT_U * 4, 256, 0, stream>>>(hb_user, Wt_src_u2i, Wt_res_i2u,
                                             fs_u2i, out_user, bias_i2u, NU_);
  gemm2_kernel<<<MT_I * 4, 256, 0, stream>>>(hb_item, Wt_src_i2u, Wt_res_u2i,
                                             fs_i2u, out_item, bias_u2i, NI_);

  // fused online-softmax gather-accumulate (items + users in one grid)
  accum_kernel<<<SCAN_N / 4, 256, 0, stream>>>(rowstart_all, ssrc,
                                               el_u2i, el_i2u, er_u2i, er_i2u,
                                               fs_u2i, fs_i2u, out_item, out_user);
}

// Round 6
// 578.436 us; speedup vs baseline: 16.0195x; 1.1522x over previous
//
#include <hip/hip_runtime.h>
#include <cstdint>
#include <cstddef>

// Problem constants
#define NU_ 100000
#define NI_ 50000
#define F_ 256
#define H_ 8
#define HD_ 512
#define NE_ 300000
#define SLOPE_ 0.2f

#define MPAD_U 100096   // NU_ rounded up to 128
#define MPAD_I 50048    // NI_ rounded up to 128
#define MT_U (MPAD_U / 128)   // 782
#define MT_I (MPAD_I / 128)   // 391

#define SCAN_N (NI_ + NU_)
#define SCAN_CHUNK 2048
#define SCAN_NB ((SCAN_N + SCAN_CHUNK - 1) / SCAN_CHUNK)  // 74

// prep kernel grid split
#define PREP_WCONV 2048
#define PREP_FOLD 32
#define PREP_HIST ((2 * NE_ + 255) / 256)   // 2344
#define PREP_NB (PREP_WCONV + PREP_FOLD + PREP_HIST)

#define ATTV_NB (SCAN_N / 4)   // 37500

typedef float f32x4 __attribute__((ext_vector_type(4)));
typedef __bf16 bf16x8 __attribute__((ext_vector_type(8)));
typedef unsigned short u16x8 __attribute__((ext_vector_type(8)));
typedef unsigned short u16x4 __attribute__((ext_vector_type(4)));

static __device__ __forceinline__ unsigned short f2bf_bits(float f) {
  unsigned u = __float_as_uint(f);
  u += 0x7fffu + ((u >> 16) & 1u);   // RNE
  return (unsigned short)(u >> 16);
}
static __device__ __forceinline__ float bf2f(unsigned short b) {
  return __uint_as_float(((unsigned)b) << 16);
}

// async global->LDS, 16B per lane; dest must be wave-uniform base + lane*16
#define GLL16(g, l)                                                        \
  __builtin_amdgcn_global_load_lds(                                        \
      (const __attribute__((address_space(1))) void*)(g),                  \
      (__attribute__((address_space(3))) void*)(l), 16, 0, 0)

// ---------------- prep: wconv (4 W -> bf16 transposed) + folds + degree histogram ----
__global__ __launch_bounds__(256) void prep_kernel(const float* __restrict__ W0,
                                                   const float* __restrict__ W1,
                                                   const float* __restrict__ W2,
                                                   const float* __restrict__ W3,
                                                   const float* __restrict__ Wd0,
                                                   const float* __restrict__ Wd1,
                                                   const float* __restrict__ a0,
                                                   const float* __restrict__ a1,
                                                   const float* __restrict__ a2,
                                                   const float* __restrict__ a3,
                                                   const int* __restrict__ dst_u2i,
                                                   const int* __restrict__ dst_i2u,
                                                   unsigned short* __restrict__ Wt,
                                                   float* __restrict__ wf,
                                                   int* __restrict__ deg) {
  int bid = blockIdx.x;
  if (bid < PREP_WCONV) {
    // Wt[m][c][f] = bf16(W_m[f][c]) ; m: 0=src_u2i 1=res_u2i 2=src_i2u 3=res_i2u
    int idx = bid * 256 + threadIdx.x;
    int m = idx >> 17;
    int r = idx & 131071;
    const float* W = (m == 0) ? W0 : (m == 1) ? W1 : (m == 2) ? W2 : W3;
    int f = r & 255, c = r >> 8;
    Wt[idx] = f2bf_bits(W[(size_t)f * HD_ + c]);
  } else if (bid < PREP_WCONV + PREP_FOLD) {
    // wf[m][h][f] = sum_d Wm[f][h*64+d]*am[h*64+d]; m: 0=wl_u2i 1=wr_u2i 2=wl_i2u 3=wr_i2u
    int b = bid - PREP_WCONV;
    int m = b >> 3;
    int idx = (b & 7) * 256 + threadIdx.x;
    const float* W = (m == 0) ? W0 : (m == 1) ? Wd0 : (m == 2) ? W2 : Wd1;
    const float* av = (m == 0) ? a0 : (m == 1) ? a1 : (m == 2) ? a2 : a3;
    int f = idx & 255, hh = idx >> 8;
    float acc = 0.f;
#pragma unroll 8
    for (int d = 0; d < 64; ++d) acc += W[(size_t)f * HD_ + hh * 64 + d] * av[hh * 64 + d];
    wf[m * 2048 + hh * 256 + f] = acc;
  } else {
    int e = (bid - PREP_WCONV - PREP_FOLD) * 256 + threadIdx.x;
    if (e < NE_) atomicAdd(&deg[dst_u2i[e]], 1);
    else if (e < 2 * NE_) atomicAdd(&deg[NI_ + dst_i2u[e - NE_]], 1);
  }
}

// ---------------- per node logits + bf16 copy of h; tail blocks do scan_reduce -------
// users rows [0,NU), items rows [NU,NU+NI); wf: [0]=wl_u2i [1]=wr_u2i [2]=wl_i2u [3]=wr_i2u
__global__ __launch_bounds__(256) void attvec_kernel(const float* __restrict__ h_user,
                                                     const float* __restrict__ h_item,
                                                     const float* __restrict__ wf,
                                                     float* __restrict__ el_u2i,
                                                     float* __restrict__ er_i2u,
                                                     float* __restrict__ el_i2u,
                                                     float* __restrict__ er_u2i,
                                                     unsigned short* __restrict__ hb_user,
                                                     unsigned short* __restrict__ hb_item,
                                                     const int* __restrict__ deg,
                                                     int* __restrict__ bsum) {
  __shared__ float sA[2048], sB[2048];
  if (blockIdx.x >= ATTV_NB) {
    // ---- scan_reduce over deg ----
    int* ilds = (int*)sA;
    int tid = threadIdx.x;
    int base = (blockIdx.x - ATTV_NB) * SCAN_CHUNK + tid * 8;
    int sum = 0;
#pragma unroll
    for (int j = 0; j < 8; ++j) sum += (base + j < SCAN_N) ? deg[base + j] : 0;
    ilds[tid] = sum;
    __syncthreads();
    for (int o = 128; o > 0; o >>= 1) {
      if (tid < o) ilds[tid] += ilds[tid + o];
      __syncthreads();
    }
    if (tid == 0) bsum[blockIdx.x - ATTV_NB] = ilds[0];
    return;
  }
  int base = blockIdx.x * 4;                   // NU_ % 4 == 0 -> block never straddles
  bool user = base < NU_;
  const float* h  = user ? h_user : h_item;
  const float* fA = user ? (wf + 0 * 2048) : (wf + 2 * 2048);  // wl_u2i / wl_i2u
  const float* fB = user ? (wf + 3 * 2048) : (wf + 1 * 2048);  // wr_i2u / wr_u2i
  float* oA = user ? el_u2i : el_i2u;
  float* oB = user ? er_i2u : er_u2i;
  unsigned short* hb = user ? hb_user : hb_item;
  int row0 = user ? base : base - NU_;
  for (int i = threadIdx.x; i < 2048; i += 256) { sA[i] = fA[i]; sB[i] = fB[i]; }
  __syncthreads();
  int wave = threadIdx.x >> 6, lane = threadIdx.x & 63;
  int row = row0 + wave;
  f32x4 v = *(const f32x4*)&h[(size_t)row * F_ + 4 * lane];
  u16x4 bv;
  bv.x = f2bf_bits(v.x); bv.y = f2bf_bits(v.y); bv.z = f2bf_bits(v.z); bv.w = f2bf_bits(v.w);
  *(u16x4*)&hb[(size_t)row * F_ + 4 * lane] = bv;
  float aA[8], aB[8];
#pragma unroll
  for (int t = 0; t < 8; ++t) {
    f32x4 wA = *(const f32x4*)&sA[t * 256 + 4 * lane];
    f32x4 wB = *(const f32x4*)&sB[t * 256 + 4 * lane];
    aA[t] = v.x * wA.x + v.y * wA.y + v.z * wA.z + v.w * wA.w;
    aB[t] = v.x * wB.x + v.y * wB.y + v.z * wB.z + v.w * wB.w;
  }
#pragma unroll
  for (int t = 0; t < 8; ++t) {
    for (int o = 32; o > 0; o >>= 1) {
      aA[t] += __shfl_down(aA[t], o);
      aB[t] += __shfl_down(aB[t], o);
    }
  }
  if (lane == 0) {
#pragma unroll
    for (int t = 0; t < 8; ++t) {
      oA[(size_t)row * 8 + t] = aA[t];
      oB[(size_t)row * 8 + t] = aB[t];
    }
  }
}

// ---------------- scan_apply (self-scans the 74 block sums) --------------------------
__global__ __launch_bounds__(256) void scan_apply_kernel(const int* __restrict__ deg,
                                                         const int* __restrict__ bsum,
                                                         int* __restrict__ rowstart,
                                                         int* __restrict__ cursor) {
  __shared__ int sb[128];
  __shared__ int lds[256];
  int tid = threadIdx.x;
  if (tid < 128) sb[tid] = (tid < SCAN_NB) ? bsum[tid] : 0;
  __syncthreads();
  for (int o = 1; o < 128; o <<= 1) {
    int t = (tid < 128 && tid >= o) ? sb[tid - o] : 0;
    __syncthreads();
    if (tid < 128) sb[tid] += t;
    __syncthreads();
  }
  int blockpref = (blockIdx.x == 0) ? 0 : sb[blockIdx.x - 1];
  int base = blockIdx.x * SCAN_CHUNK + tid * 8;
  int v[8];
  int sum = 0;
#pragma unroll
  for (int j = 0; j < 8; ++j) {
    v[j] = (base + j < SCAN_N) ? deg[base + j] : 0;
    sum += v[j];
  }
  lds[tid] = sum;
  __syncthreads();
  for (int o = 1; o < 256; o <<= 1) {
    int t = (tid >= o) ? lds[tid - o] : 0;
    __syncthreads();
    lds[tid] += t;
    __syncthreads();
  }
  int run = blockpref + lds[tid] - sum;
#pragma unroll
  for (int j = 0; j < 8; ++j) {
    if (base + j < SCAN_N) { rowstart[base + j] = run; cursor[base + j] = run; }
    run += v[j];
  }
  if (blockIdx.x == 0 && tid == 0) rowstart[SCAN_N] = 2 * NE_;
}

// ---------------- bin: scatter source node ids into CSR slots ----------------
__global__ __launch_bounds__(256) void bin_kernel(const int* __restrict__ src_u2i,
                                                  const int* __restrict__ dst_u2i,
                                                  const int* __restrict__ src_i2u,
                                                  const int* __restrict__ dst_i2u,
                                                  int* __restrict__ cursor,
                                                  int* __restrict__ ssrc) {
  int e = blockIdx.x * 256 + threadIdx.x;
  int de, se;
  if (e < NE_) { de = dst_u2i[e]; se = src_u2i[e]; }
  else if (e < 2 * NE_) { de = NI_ + dst_i2u[e - NE_]; se = src_i2u[e - NE_]; }
  else return;
  int pos = atomicAdd(&cursor[de], 1);
  ssrc[pos] = se;
}

// ---------------- dual GEMM, both node types in one launch ---------------------------
// C1 = A@B1 -> bf16 fs;  C2 = A@B2 + bias -> bf16 res (ws).
__global__ __launch_bounds__(256) void gemm2_kernel(const unsigned short* __restrict__ hb_user,
                                                    const unsigned short* __restrict__ hb_item,
                                                    const unsigned short* __restrict__ Wt,
                                                    unsigned short* __restrict__ fs_u2i,
                                                    unsigned short* __restrict__ fs_i2u,
                                                    unsigned short* __restrict__ res_user,
                                                    unsigned short* __restrict__ res_item,
                                                    const float* __restrict__ bias_u2i,
                                                    const float* __restrict__ bias_i2u) {
  __shared__ unsigned short lds[2][3][128][32];   // 48 KB
  int bid = blockIdx.x;
  bool user = bid < MT_U * 4;
  if (!user) bid -= MT_U * 4;
  const unsigned short* Ab  = user ? hb_user : hb_item;
  const unsigned short* B1t = user ? (Wt + 0 * HD_ * F_) : (Wt + 2 * HD_ * F_);  // src_u2i/src_i2u
  const unsigned short* B2t = user ? (Wt + 3 * HD_ * F_) : (Wt + 1 * HD_ * F_);  // res_i2u/res_u2i
  unsigned short* fs  = user ? fs_u2i : fs_i2u;
  unsigned short* res = user ? res_user : res_item;
  const float* bias = user ? bias_i2u : bias_u2i;
  int M = user ? NU_ : NI_;

  int tid = threadIdx.x;
  int lane = tid & 63;
  int wave = tid >> 6;
  int wm = wave >> 1, wn = wave & 1;
  int mt = bid >> 2, nt = bid & 3;
  int bm = mt * 128, bn = nt * 128;
  f32x4 acc1[4][4] = {};
  f32x4 acc2[4][4] = {};
  int lr = lane & 15;
  int kk = (lane >> 4) * 8;

  int r0 = tid >> 2;            // rows 0..63 (it=0)
  int c0 = (tid & 3) << 3;      // 8 bf16 = 16 B
  const unsigned short* gA  = &Ab [(size_t)(bm + r0) * 256 + c0];
  const unsigned short* gB1 = &B1t[(size_t)(bn + r0) * 256 + c0];
  const unsigned short* gB2 = &B2t[(size_t)(bn + r0) * 256 + c0];

#define STAGE(buf, t)                                                       \
  do {                                                                      \
    int k0_ = (t) * 32;                                                     \
    GLL16(gA  + k0_,          &lds[buf][0][r0][c0]);                        \
    GLL16(gA  + k0_ + 64*256, &lds[buf][0][r0 + 64][c0]);                   \
    GLL16(gB1 + k0_,          &lds[buf][1][r0][c0]);                        \
    GLL16(gB1 + k0_ + 64*256, &lds[buf][1][r0 + 64][c0]);                   \
    GLL16(gB2 + k0_,          &lds[buf][2][r0][c0]);                        \
    GLL16(gB2 + k0_ + 64*256, &lds[buf][2][r0 + 64][c0]);                   \
  } while (0)

  STAGE(0, 0);
  __syncthreads();
  int cur = 0;
#pragma unroll
  for (int t = 0; t < 8; ++t) {
    if (t < 7) STAGE(cur ^ 1, t + 1);
    bf16x8 af[4], b1[4], b2[4];
#pragma unroll
    for (int m = 0; m < 4; ++m)
      af[m] = __builtin_bit_cast(bf16x8, *(const u16x8*)&lds[cur][0][wm * 64 + m * 16 + lr][kk]);
#pragma unroll
    for (int n = 0; n < 4; ++n) {
      b1[n] = __builtin_bit_cast(bf16x8, *(const u16x8*)&lds[cur][1][wn * 64 + n * 16 + lr][kk]);
      b2[n] = __builtin_bit_cast(bf16x8, *(const u16x8*)&lds[cur][2][wn * 64 + n * 16 + lr][kk]);
    }
#pragma unroll
    for (int m = 0; m < 4; ++m)
#pragma unroll
      for (int n = 0; n < 4; ++n) {
        acc1[m][n] = __builtin_amdgcn_mfma_f32_16x16x32_bf16(af[m], b1[n], acc1[m][n], 0, 0, 0);
        acc2[m][n] = __builtin_amdgcn_mfma_f32_16x16x32_bf16(af[m], b2[n], acc2[m][n], 0, 0, 0);
      }
    __syncthreads();
    cur ^= 1;
  }
#undef STAGE

  int rg = (lane >> 4) * 4;
#pragma unroll
  for (int m = 0; m < 4; ++m) {
#pragma unroll
    for (int r = 0; r < 4; ++r) {
      int row = bm + wm * 64 + m * 16 + rg + r;
      if (row >= M) continue;
#pragma unroll
      for (int n = 0; n < 4; ++n) {
        int col = bn + wn * 64 + n * 16 + lr;
        fs[(size_t)row * HD_ + col]  = f2bf_bits(acc1[m][n][r]);
        res[(size_t)row * HD_ + col] = f2bf_bits(acc2[m][n][r] + bias[col]);
      }
    }
  }
}

// ---------------- fused accum: online softmax + weighted fs gather + residual --------
// Write-only on out (covers every node; zero-degree nodes get res only).
__global__ __launch_bounds__(256) void accum_kernel(const int* __restrict__ rowstart,
                                                    const int* __restrict__ ssrc,
                                                    const float* __restrict__ el_u2i,
                                                    const float* __restrict__ el_i2u,
                                                    const float* __restrict__ er_u2i,
                                                    const float* __restrict__ er_i2u,
                                                    const unsigned short* __restrict__ fs_u2i,
                                                    const unsigned short* __restrict__ fs_i2u,
                                                    const unsigned short* __restrict__ res_user,
                                                    const unsigned short* __restrict__ res_item,
                                                    float* __restrict__ out_item,
                                                    float* __restrict__ out_user) {
  int n = blockIdx.x * 4 + (threadIdx.x >> 6);
  int lane = threadIdx.x & 63;
  bool item = n < NI_;
  int ln = item ? n : n - NI_;
  const unsigned short* res = item ? res_item : res_user;
  float* out = (item ? out_item : out_user) + (size_t)ln * HD_;
  int r0 = rowstart[n], r1 = rowstart[n + 1];
  float acc[8] = {};
  if (r0 < r1) {
    const float* el = item ? el_u2i : el_i2u;
    const float* er = item ? er_u2i : er_i2u;
    const unsigned short* fs = item ? fs_u2i : fs_i2u;
    int hh = lane >> 3;
    float erh = er[(size_t)ln * 8 + hh];
    float m = -3.0e38f, s = 0.f;
    int k = r0;
    for (; k + 2 <= r1; k += 2) {
      int s0 = ssrc[k], s1 = ssrc[k + 1];
      float e0 = el[(size_t)s0 * 8 + hh] + erh;
      float e1 = el[(size_t)s1 * 8 + hh] + erh;
      e0 = e0 > 0.f ? e0 : SLOPE_ * e0;
      e1 = e1 > 0.f ? e1 : SLOPE_ * e1;
      u16x8 v0 = *(const u16x8*)&fs[(size_t)s0 * HD_ + lane * 8];
      u16x8 v1 = *(const u16x8*)&fs[(size_t)s1 * HD_ + lane * 8];
      float mm = fmaxf(e0, e1);
      if (mm > m) {
        float r = __expf(m - mm);
        s *= r;
#pragma unroll
        for (int j = 0; j < 8; ++j) acc[j] *= r;
        m = mm;
      }
      float x0 = __expf(e0 - m), x1 = __expf(e1 - m);
      s += x0 + x1;
#pragma unroll
      for (int j = 0; j < 8; ++j)
        acc[j] += x0 * bf2f((unsigned short)v0[j]) + x1 * bf2f((unsigned short)v1[j]);
    }
    if (k < r1) {
      int s0 = ssrc[k];
      float e0 = el[(size_t)s0 * 8 + hh] + erh;
      e0 = e0 > 0.f ? e0 : SLOPE_ * e0;
      u16x8 v0 = *(const u16x8*)&fs[(size_t)s0 * HD_ + lane * 8];
      if (e0 > m) {
        float r = __expf(m - e0);
        s *= r;
#pragma unroll
        for (int j = 0; j < 8; ++j) acc[j] *= r;
        m = e0;
      }
      float x0 = __expf(e0 - m);
      s += x0;
#pragma unroll
      for (int j = 0; j < 8; ++j) acc[j] += x0 * bf2f((unsigned short)v0[j]);
    }
    float inv = 1.f / s;
#pragma unroll
    for (int j = 0; j < 8; ++j) acc[j] *= inv;
  }
  u16x8 rv = *(const u16x8*)&res[(size_t)ln * HD_ + lane * 8];
  f32x4 o0, o1;
#pragma unroll
  for (int j = 0; j < 4; ++j) {
    o0[j] = acc[j] + bf2f((unsigned short)rv[j]);
    o1[j] = acc[4 + j] + bf2f((unsigned short)rv[4 + j]);
  }
  float* op = out + lane * 8;
  *(f32x4*)op = o0;
  *(f32x4*)(op + 4) = o1;
}

// =====================================================================================
extern "C" void kernel_launch(void* const* d_in, const int* in_sizes, int n_in,
                              void* d_out, int out_size, void* d_ws, size_t ws_size,
                              hipStream_t stream) {
  const float* h_user    = (const float*)d_in[0];
  const float* h_item    = (const float*)d_in[1];
  const int*   src_u2i   = (const int*)d_in[2];
  const int*   dst_u2i   = (const int*)d_in[3];
  const int*   src_i2u   = (const int*)d_in[4];
  const int*   dst_i2u   = (const int*)d_in[5];
  const float* W_src_u2i = (const float*)d_in[6];
  const float* W_dst_u2i = (const float*)d_in[7];
  const float* al_u2i    = (const float*)d_in[8];
  const float* ar_u2i    = (const float*)d_in[9];
  const float* bias_u2i  = (const float*)d_in[10];
  const float* W_res_u2i = (const float*)d_in[11];
  const float* W_src_i2u = (const float*)d_in[12];
  const float* W_dst_i2u = (const float*)d_in[13];
  const float* al_i2u    = (const float*)d_in[14];
  const float* ar_i2u    = (const float*)d_in[15];
  const float* bias_i2u  = (const float*)d_in[16];
  const float* W_res_i2u = (const float*)d_in[17];

  float* out_user = (float*)d_out;                       // [NU,512]
  float* out_item = (float*)d_out + (size_t)NU_ * HD_;   // [NI,512]

  char* ws = (char*)d_ws;
  size_t off = 0;
  auto take = [&](size_t bytes) -> char* {
    char* p = ws + off;
    off += (bytes + 255) & ~(size_t)255;
    return p;
  };
  unsigned short* fs_u2i  = (unsigned short*)take((size_t)NU_ * HD_ * 2);
  unsigned short* fs_i2u  = (unsigned short*)take((size_t)NI_ * HD_ * 2);
  unsigned short* res_user = (unsigned short*)take((size_t)NU_ * HD_ * 2);
  unsigned short* res_item = (unsigned short*)take((size_t)NI_ * HD_ * 2);
  unsigned short* hb_user = (unsigned short*)take((size_t)MPAD_U * F_ * 2);
  unsigned short* hb_item = (unsigned short*)take((size_t)MPAD_I * F_ * 2);
  // Wt: [0]=src_u2i [1]=res_u2i [2]=src_i2u [3]=res_i2u, each [512][256] bf16
  unsigned short* Wt = (unsigned short*)take((size_t)4 * HD_ * F_ * 2);
  // wf: [0]=wl_u2i [1]=wr_u2i [2]=wl_i2u [3]=wr_i2u
  float* wf = (float*)take((size_t)4 * 2048 * 4);
  float* el_u2i = (float*)take((size_t)NU_ * 8 * 4);
  float* er_i2u = (float*)take((size_t)NU_ * 8 * 4);
  float* el_i2u = (float*)take((size_t)NI_ * 8 * 4);
  float* er_u2i = (float*)take((size_t)NI_ * 8 * 4);
  int* deg_all      = (int*)take((size_t)SCAN_N * 4);        // zeroed
  int* rowstart_all = (int*)take((size_t)(SCAN_N + 1) * 4);
  int* cursor_all   = (int*)take((size_t)SCAN_N * 4);
  int* bsum         = (int*)take((size_t)128 * 4);
  int* ssrc         = (int*)take((size_t)2 * NE_ * 4);

  hipMemsetAsync(deg_all, 0, (size_t)SCAN_N * 4, stream);

  // wconv + folds + degree histogram (one launch)
  prep_kernel<<<PREP_NB, 256, 0, stream>>>(W_src_u2i, W_res_u2i, W_src_i2u, W_res_i2u,
                                           W_dst_u2i, W_dst_i2u,
                                           al_u2i, ar_u2i, al_i2u, ar_i2u,
                                           dst_u2i, dst_i2u, Wt, wf, deg_all);

  // per-node logits + bf16 h copy; tail blocks: scan_reduce
  attvec_kernel<<<ATTV_NB + SCAN_NB, 256, 0, stream>>>(h_user, h_item, wf,
                                                       el_u2i, er_i2u, el_i2u, er_u2i,
                                                       hb_user, hb_item, deg_all, bsum);

  // dual GEMMs, both types in one launch: fs + res (both bf16, ws)
  gemm2_kernel<<<(MT_U + MT_I) * 4, 256, 0, stream>>>(hb_user, hb_item, Wt,
                                                      fs_u2i, fs_i2u, res_user, res_item,
                                                      bias_u2i, bias_i2u);

  // CSR: scan (self-contained) + bin
  scan_apply_kernel<<<SCAN_NB, 256, 0, stream>>>(deg_all, bsum, rowstart_all, cursor_all);
  constexpr int EB2 = (2 * NE_ + 255) / 256;
  bin_kernel<<<EB2, 256, 0, stream>>>(src_u2i, dst_u2i, src_i2u, dst_i2u, cursor_all, ssrc);

  // fused online-softmax gather-accumulate + residual, write-only out
  accum_kernel<<<SCAN_N / 4, 256, 0, stream>>>(rowstart_all, ssrc,
                                               el_u2i, el_i2u, er_u2i, er_i2u,
                                               fs_u2i, fs_i2u, res_user, res_item,
                                               out_item, out_user);
}

// Round 7
// 508.051 us; speedup vs baseline: 18.2388x; 1.1385x over previous
//
#include <hip/hip_runtime.h>
#include <cstdint>
#include <cstddef>

// Problem constants
#define NU_ 100000
#define NI_ 50000
#define F_ 256
#define H_ 8
#define HD_ 512
#define NE_ 300000
#define SLOPE_ 0.2f

#define MPAD_U 100096   // NU_ rounded up to 128
#define MPAD_I 50048    // NI_ rounded up to 128
#define MT_U (MPAD_U / 128)   // 782
#define MT_I (MPAD_I / 128)   // 391
#define GEMM_NB ((MT_U + MT_I) * 4)   // 4692

#define SCAN_N (NI_ + NU_)
#define SCAN_CHUNK 2048
#define SCAN_NB ((SCAN_N + SCAN_CHUNK - 1) / SCAN_CHUNK)  // 74

// prep kernel grid split: copy | wconv | fold | hist
#define PREP_COPY_U (NU_ * F_ / 2048)          // 12500
#define PREP_COPY_I (NI_ * F_ / 2048)          // 6250
#define PREP_COPY (PREP_COPY_U + PREP_COPY_I)  // 18750
#define PREP_WCONV 2048
#define PREP_FOLD 32
#define PREP_HIST ((2 * NE_ + 255) / 256)      // 2344
#define PREP_NB (PREP_COPY + PREP_WCONV + PREP_FOLD + PREP_HIST)

typedef float f32x4 __attribute__((ext_vector_type(4)));
typedef __bf16 bf16x8 __attribute__((ext_vector_type(8)));
typedef unsigned short u16x8 __attribute__((ext_vector_type(8)));
typedef unsigned short u16x4 __attribute__((ext_vector_type(4)));

static __device__ __forceinline__ unsigned short f2bf_bits(float f) {
  unsigned u = __float_as_uint(f);
  u += 0x7fffu + ((u >> 16) & 1u);   // RNE
  return (unsigned short)(u >> 16);
}
static __device__ __forceinline__ float bf2f(unsigned short b) {
  return __uint_as_float(((unsigned)b) << 16);
}

// async global->LDS, 16B per lane; dest must be wave-uniform base + lane*16
#define GLL16(g, l)                                                        \
  __builtin_amdgcn_global_load_lds(                                        \
      (const __attribute__((address_space(1))) void*)(g),                  \
      (__attribute__((address_space(3))) void*)(l), 16, 0, 0)

// ---------------- prep: h->bf16 copy + wconv + folds(->bf16 wfb) + degree histogram --
// wfb: [0]=user [16][256] rows 0-7 wl_u2i, 8-15 wr_i2u; [1]=item rows 0-7 wl_i2u, 8-15 wr_u2i
__global__ __launch_bounds__(256) void prep_kernel(const float* __restrict__ h_user,
                                                   const float* __restrict__ h_item,
                                                   const float* __restrict__ W0,
                                                   const float* __restrict__ W1,
                                                   const float* __restrict__ W2,
                                                   const float* __restrict__ W3,
                                                   const float* __restrict__ Wd0,
                                                   const float* __restrict__ Wd1,
                                                   const float* __restrict__ a0,
                                                   const float* __restrict__ a1,
                                                   const float* __restrict__ a2,
                                                   const float* __restrict__ a3,
                                                   const int* __restrict__ dst_u2i,
                                                   const int* __restrict__ dst_i2u,
                                                   unsigned short* __restrict__ hb_user,
                                                   unsigned short* __restrict__ hb_item,
                                                   unsigned short* __restrict__ Wt,
                                                   unsigned short* __restrict__ wfb,
                                                   int* __restrict__ deg) {
  int bid = blockIdx.x;
  if (bid < PREP_COPY) {
    // f32 h -> bf16 hb, 8 elems/thread
    bool user = bid < PREP_COPY_U;
    const float* h = user ? h_user : h_item;
    unsigned short* hb = user ? hb_user : hb_item;
    size_t base = (size_t)(user ? bid : bid - PREP_COPY_U) * 2048 + threadIdx.x * 8;
    f32x4 a = *(const f32x4*)&h[base];
    f32x4 b = *(const f32x4*)&h[base + 4];
    u16x8 o;
    o[0] = f2bf_bits(a.x); o[1] = f2bf_bits(a.y); o[2] = f2bf_bits(a.z); o[3] = f2bf_bits(a.w);
    o[4] = f2bf_bits(b.x); o[5] = f2bf_bits(b.y); o[6] = f2bf_bits(b.z); o[7] = f2bf_bits(b.w);
    *(u16x8*)&hb[base] = o;
  } else if (bid < PREP_COPY + PREP_WCONV) {
    // Wt[m][c][f] = bf16(W_m[f][c]) ; m: 0=src_u2i 1=res_u2i 2=src_i2u 3=res_i2u
    int idx = (bid - PREP_COPY) * 256 + threadIdx.x;
    int m = idx >> 17;
    int r = idx & 131071;
    const float* W = (m == 0) ? W0 : (m == 1) ? W1 : (m == 2) ? W2 : W3;
    int f = r & 255, c = r >> 8;
    Wt[idx] = f2bf_bits(W[(size_t)f * HD_ + c]);
  } else if (bid < PREP_COPY + PREP_WCONV + PREP_FOLD) {
    // fold m: 0=wl_u2i(W0,a0) 1=wr_u2i(Wd0,a1) 2=wl_i2u(W2,a2) 3=wr_i2u(Wd1,a3)
    int b = bid - PREP_COPY - PREP_WCONV;
    int m = b >> 3;
    int idx = (b & 7) * 256 + threadIdx.x;
    const float* W = (m == 0) ? W0 : (m == 1) ? Wd0 : (m == 2) ? W2 : Wd1;
    const float* av = (m == 0) ? a0 : (m == 1) ? a1 : (m == 2) ? a2 : a3;
    int f = idx & 255, hh = idx >> 8;
    float acc = 0.f;
#pragma unroll 8
    for (int d = 0; d < 64; ++d) acc += W[(size_t)f * HD_ + hh * 64 + d] * av[hh * 64 + d];
    int buf = (m == 0 || m == 3) ? 0 : 1;
    int rowoff = (m == 1 || m == 3) ? 8 : 0;
    wfb[buf * 4096 + (rowoff + hh) * 256 + f] = f2bf_bits(acc);
  } else {
    int e = (bid - PREP_COPY - PREP_WCONV - PREP_FOLD) * 256 + threadIdx.x;
    if (e < NE_) atomicAdd(&deg[dst_u2i[e]], 1);
    else if (e < 2 * NE_) atomicAdd(&deg[NI_ + dst_i2u[e - NE_]], 1);
  }
}

// ---------------- triple-output GEMM + scan_reduce tail ------------------------------
// C1 = A@B1 -> bf16 fs;  C2 = A@B2 + bias -> bf16 res;  C3 = A@wf^T -> f32 el/er (nt==0)
__global__ __launch_bounds__(256) void gemm2_kernel(const unsigned short* __restrict__ hb_user,
                                                    const unsigned short* __restrict__ hb_item,
                                                    const unsigned short* __restrict__ Wt,
                                                    const unsigned short* __restrict__ wfb,
                                                    unsigned short* __restrict__ fs_u2i,
                                                    unsigned short* __restrict__ fs_i2u,
                                                    unsigned short* __restrict__ res_user,
                                                    unsigned short* __restrict__ res_item,
                                                    const float* __restrict__ bias_u2i,
                                                    const float* __restrict__ bias_i2u,
                                                    float* __restrict__ el_u2i,
                                                    float* __restrict__ er_i2u,
                                                    float* __restrict__ el_i2u,
                                                    float* __restrict__ er_u2i,
                                                    const int* __restrict__ deg,
                                                    int* __restrict__ bsum) {
  __shared__ unsigned short lds[2][3][128][32];   // 48 KB
  __shared__ unsigned short wflds[2][16][32];     // 2 KB
  if (blockIdx.x >= GEMM_NB) {
    // ---- scan_reduce over deg ----
    int* ilds = (int*)&lds[0][0][0][0];
    int tid = threadIdx.x;
    int base = (blockIdx.x - GEMM_NB) * SCAN_CHUNK + tid * 8;
    int sum = 0;
#pragma unroll
    for (int j = 0; j < 8; ++j) sum += (base + j < SCAN_N) ? deg[base + j] : 0;
    ilds[tid] = sum;
    __syncthreads();
    for (int o = 128; o > 0; o >>= 1) {
      if (tid < o) ilds[tid] += ilds[tid + o];
      __syncthreads();
    }
    if (tid == 0) bsum[blockIdx.x - GEMM_NB] = ilds[0];
    return;
  }
  int bid = blockIdx.x;
  bool user = bid < MT_U * 4;
  if (!user) bid -= MT_U * 4;
  const unsigned short* Ab  = user ? hb_user : hb_item;
  const unsigned short* B1t = user ? (Wt + 0 * HD_ * F_) : (Wt + 2 * HD_ * F_);  // src
  const unsigned short* B2t = user ? (Wt + 3 * HD_ * F_) : (Wt + 1 * HD_ * F_);  // res
  const unsigned short* wfs = user ? wfb : (wfb + 4096);
  unsigned short* fs  = user ? fs_u2i : fs_i2u;
  unsigned short* res = user ? res_user : res_item;
  const float* bias = user ? bias_i2u : bias_u2i;
  int M = user ? NU_ : NI_;

  int tid = threadIdx.x;
  int lane = tid & 63;
  int wave = tid >> 6;
  int wm = wave >> 1, wn = wave & 1;
  int mt = bid >> 2, nt = bid & 3;
  int bm = mt * 128, bn = nt * 128;
  f32x4 acc1[4][4] = {};
  f32x4 acc2[4][4] = {};
  f32x4 acc3[4] = {};
  int lr = lane & 15;
  int kk = (lane >> 4) * 8;

  int r0 = tid >> 2;            // rows 0..63 (it=0)
  int c0 = (tid & 3) << 3;      // 8 bf16 = 16 B
  const unsigned short* gA  = &Ab [(size_t)(bm + r0) * 256 + c0];
  const unsigned short* gB1 = &B1t[(size_t)(bn + r0) * 256 + c0];
  const unsigned short* gB2 = &B2t[(size_t)(bn + r0) * 256 + c0];
  const unsigned short* gW  = &wfs[(size_t)(tid >> 2) * 256 + c0];   // valid for tid<64

#define STAGE(buf, t)                                                       \
  do {                                                                      \
    int k0_ = (t) * 32;                                                     \
    GLL16(gA  + k0_,          &lds[buf][0][r0][c0]);                        \
    GLL16(gA  + k0_ + 64*256, &lds[buf][0][r0 + 64][c0]);                   \
    GLL16(gB1 + k0_,          &lds[buf][1][r0][c0]);                        \
    GLL16(gB1 + k0_ + 64*256, &lds[buf][1][r0 + 64][c0]);                   \
    GLL16(gB2 + k0_,          &lds[buf][2][r0][c0]);                        \
    GLL16(gB2 + k0_ + 64*256, &lds[buf][2][r0 + 64][c0]);                   \
    if (nt == 0 && tid < 64) GLL16(gW + k0_, &wflds[buf][tid >> 2][c0]);    \
  } while (0)

  STAGE(0, 0);
  __syncthreads();
  int cur = 0;
#pragma unroll
  for (int t = 0; t < 8; ++t) {
    if (t < 7) STAGE(cur ^ 1, t + 1);
    bf16x8 af[4], b1[4], b2[4];
#pragma unroll
    for (int m = 0; m < 4; ++m)
      af[m] = __builtin_bit_cast(bf16x8, *(const u16x8*)&lds[cur][0][wm * 64 + m * 16 + lr][kk]);
#pragma unroll
    for (int n = 0; n < 4; ++n) {
      b1[n] = __builtin_bit_cast(bf16x8, *(const u16x8*)&lds[cur][1][wn * 64 + n * 16 + lr][kk]);
      b2[n] = __builtin_bit_cast(bf16x8, *(const u16x8*)&lds[cur][2][wn * 64 + n * 16 + lr][kk]);
    }
#pragma unroll
    for (int m = 0; m < 4; ++m)
#pragma unroll
      for (int n = 0; n < 4; ++n) {
        acc1[m][n] = __builtin_amdgcn_mfma_f32_16x16x32_bf16(af[m], b1[n], acc1[m][n], 0, 0, 0);
        acc2[m][n] = __builtin_amdgcn_mfma_f32_16x16x32_bf16(af[m], b2[n], acc2[m][n], 0, 0, 0);
      }
    if (nt == 0) {
      bf16x8 b3 = __builtin_bit_cast(bf16x8, *(const u16x8*)&wflds[cur][lr][kk]);
#pragma unroll
      for (int m = 0; m < 4; ++m)
        acc3[m] = __builtin_amdgcn_mfma_f32_16x16x32_bf16(af[m], b3, acc3[m], 0, 0, 0);
    }
    __syncthreads();
    cur ^= 1;
  }
#undef STAGE

  int rg = (lane >> 4) * 4;
#pragma unroll
  for (int m = 0; m < 4; ++m) {
#pragma unroll
    for (int r = 0; r < 4; ++r) {
      int row = bm + wm * 64 + m * 16 + rg + r;
      if (row >= M) continue;
#pragma unroll
      for (int n = 0; n < 4; ++n) {
        int col = bn + wn * 64 + n * 16 + lr;
        fs[(size_t)row * HD_ + col]  = f2bf_bits(acc1[m][n][r]);
        res[(size_t)row * HD_ + col] = f2bf_bits(acc2[m][n][r] + bias[col]);
      }
    }
  }
  if (nt == 0 && wn == 0) {
    float* elp = user ? el_u2i : el_i2u;
    float* erp = user ? er_i2u : er_u2i;
#pragma unroll
    for (int m = 0; m < 4; ++m) {
#pragma unroll
      for (int r = 0; r < 4; ++r) {
        int row = bm + wm * 64 + m * 16 + rg + r;
        if (row >= M) continue;
        if (lr < 8) elp[(size_t)row * 8 + lr] = acc3[m][r];
        else        erp[(size_t)row * 8 + lr - 8] = acc3[m][r];
      }
    }
  }
}

// ---------------- scan_apply (self-scans the 74 block sums) --------------------------
__global__ __launch_bounds__(256) void scan_apply_kernel(const int* __restrict__ deg,
                                                         const int* __restrict__ bsum,
                                                         int* __restrict__ rowstart,
                                                         int* __restrict__ cursor) {
  __shared__ int sb[128];
  __shared__ int lds[256];
  int tid = threadIdx.x;
  if (tid < 128) sb[tid] = (tid < SCAN_NB) ? bsum[tid] : 0;
  __syncthreads();
  for (int o = 1; o < 128; o <<= 1) {
    int t = (tid < 128 && tid >= o) ? sb[tid - o] : 0;
    __syncthreads();
    if (tid < 128) sb[tid] += t;
    __syncthreads();
  }
  int blockpref = (blockIdx.x == 0) ? 0 : sb[blockIdx.x - 1];
  int base = blockIdx.x * SCAN_CHUNK + tid * 8;
  int v[8];
  int sum = 0;
#pragma unroll
  for (int j = 0; j < 8; ++j) {
    v[j] = (base + j < SCAN_N) ? deg[base + j] : 0;
    sum += v[j];
  }
  lds[tid] = sum;
  __syncthreads();
  for (int o = 1; o < 256; o <<= 1) {
    int t = (tid >= o) ? lds[tid - o] : 0;
    __syncthreads();
    lds[tid] += t;
    __syncthreads();
  }
  int run = blockpref + lds[tid] - sum;
#pragma unroll
  for (int j = 0; j < 8; ++j) {
    if (base + j < SCAN_N) { rowstart[base + j] = run; cursor[base + j] = run; }
    run += v[j];
  }
  if (blockIdx.x == 0 && tid == 0) rowstart[SCAN_N] = 2 * NE_;
}

// ---------------- bin: scatter source node ids into CSR slots ----------------
__global__ __launch_bounds__(256) void bin_kernel(const int* __restrict__ src_u2i,
                                                  const int* __restrict__ dst_u2i,
                                                  const int* __restrict__ src_i2u,
                                                  const int* __restrict__ dst_i2u,
                                                  int* __restrict__ cursor,
                                                  int* __restrict__ ssrc) {
  int e = blockIdx.x * 256 + threadIdx.x;
  int de, se;
  if (e < NE_) { de = dst_u2i[e]; se = src_u2i[e]; }
  else if (e < 2 * NE_) { de = NI_ + dst_i2u[e - NE_]; se = src_i2u[e - NE_]; }
  else return;
  int pos = atomicAdd(&cursor[de], 1);
  ssrc[pos] = se;
}

// ---------------- fused accum: online softmax + weighted fs gather + residual --------
__global__ __launch_bounds__(256) void accum_kernel(const int* __restrict__ rowstart,
                                                    const int* __restrict__ ssrc,
                                                    const float* __restrict__ el_u2i,
                                                    const float* __restrict__ el_i2u,
                                                    const float* __restrict__ er_u2i,
                                                    const float* __restrict__ er_i2u,
                                                    const unsigned short* __restrict__ fs_u2i,
                                                    const unsigned short* __restrict__ fs_i2u,
                                                    const unsigned short* __restrict__ res_user,
                                                    const unsigned short* __restrict__ res_item,
                                                    float* __restrict__ out_item,
                                                    float* __restrict__ out_user) {
  int n = blockIdx.x * 4 + (threadIdx.x >> 6);
  int lane = threadIdx.x & 63;
  bool item = n < NI_;
  int ln = item ? n : n - NI_;
  const unsigned short* res = item ? res_item : res_user;
  float* out = (item ? out_item : out_user) + (size_t)ln * HD_;
  int r0 = rowstart[n], r1 = rowstart[n + 1];
  float acc[8] = {};
  if (r0 < r1) {
    const float* el = item ? el_u2i : el_i2u;
    const float* er = item ? er_u2i : er_i2u;
    const unsigned short* fs = item ? fs_u2i : fs_i2u;
    int hh = lane >> 3;
    float erh = er[(size_t)ln * 8 + hh];
    float m = -3.0e38f, s = 0.f;
    int k = r0;
    for (; k + 2 <= r1; k += 2) {
      int s0 = ssrc[k], s1 = ssrc[k + 1];
      float e0 = el[(size_t)s0 * 8 + hh] + erh;
      float e1 = el[(size_t)s1 * 8 + hh] + erh;
      e0 = e0 > 0.f ? e0 : SLOPE_ * e0;
      e1 = e1 > 0.f ? e1 : SLOPE_ * e1;
      u16x8 v0 = *(const u16x8*)&fs[(size_t)s0 * HD_ + lane * 8];
      u16x8 v1 = *(const u16x8*)&fs[(size_t)s1 * HD_ + lane * 8];
      float mm = fmaxf(e0, e1);
      if (mm > m) {
        float r = __expf(m - mm);
        s *= r;
#pragma unroll
        for (int j = 0; j < 8; ++j) acc[j] *= r;
        m = mm;
      }
      float x0 = __expf(e0 - m), x1 = __expf(e1 - m);
      s += x0 + x1;
#pragma unroll
      for (int j = 0; j < 8; ++j)
        acc[j] += x0 * bf2f((unsigned short)v0[j]) + x1 * bf2f((unsigned short)v1[j]);
    }
    if (k < r1) {
      int s0 = ssrc[k];
      float e0 = el[(size_t)s0 * 8 + hh] + erh;
      e0 = e0 > 0.f ? e0 : SLOPE_ * e0;
      u16x8 v0 = *(const u16x8*)&fs[(size_t)s0 * HD_ + lane * 8];
      if (e0 > m) {
        float r = __expf(m - e0);
        s *= r;
#pragma unroll
        for (int j = 0; j < 8; ++j) acc[j] *= r;
        m = e0;
      }
      float x0 = __expf(e0 - m);
      s += x0;
#pragma unroll
      for (int j = 0; j < 8; ++j) acc[j] += x0 * bf2f((unsigned short)v0[j]);
    }
    float inv = 1.f / s;
#pragma unroll
    for (int j = 0; j < 8; ++j) acc[j] *= inv;
  }
  u16x8 rv = *(const u16x8*)&res[(size_t)ln * HD_ + lane * 8];
  f32x4 o0, o1;
#pragma unroll
  for (int j = 0; j < 4; ++j) {
    o0[j] = acc[j] + bf2f((unsigned short)rv[j]);
    o1[j] = acc[4 + j] + bf2f((unsigned short)rv[4 + j]);
  }
  float* op = out + lane * 8;
  *(f32x4*)op = o0;
  *(f32x4*)(op + 4) = o1;
}

// =====================================================================================
extern "C" void kernel_launch(void* const* d_in, const int* in_sizes, int n_in,
                              void* d_out, int out_size, void* d_ws, size_t ws_size,
                              hipStream_t stream) {
  const float* h_user    = (const float*)d_in[0];
  const float* h_item    = (const float*)d_in[1];
  const int*   src_u2i   = (const int*)d_in[2];
  const int*   dst_u2i   = (const int*)d_in[3];
  const int*   src_i2u   = (const int*)d_in[4];
  const int*   dst_i2u   = (const int*)d_in[5];
  const float* W_src_u2i = (const float*)d_in[6];
  const float* W_dst_u2i = (const float*)d_in[7];
  const float* al_u2i    = (const float*)d_in[8];
  const float* ar_u2i    = (const float*)d_in[9];
  const float* bias_u2i  = (const float*)d_in[10];
  const float* W_res_u2i = (const float*)d_in[11];
  const float* W_src_i2u = (const float*)d_in[12];
  const float* W_dst_i2u = (const float*)d_in[13];
  const float* al_i2u    = (const float*)d_in[14];
  const float* ar_i2u    = (const float*)d_in[15];
  const float* bias_i2u  = (const float*)d_in[16];
  const float* W_res_i2u = (const float*)d_in[17];

  float* out_user = (float*)d_out;                       // [NU,512]
  float* out_item = (float*)d_out + (size_t)NU_ * HD_;   // [NI,512]

  char* ws = (char*)d_ws;
  size_t off = 0;
  auto take = [&](size_t bytes) -> char* {
    char* p = ws + off;
    off += (bytes + 255) & ~(size_t)255;
    return p;
  };
  unsigned short* fs_u2i   = (unsigned short*)take((size_t)NU_ * HD_ * 2);
  unsigned short* fs_i2u   = (unsigned short*)take((size_t)NI_ * HD_ * 2);
  unsigned short* res_user = (unsigned short*)take((size_t)NU_ * HD_ * 2);
  unsigned short* res_item = (unsigned short*)take((size_t)NI_ * HD_ * 2);
  unsigned short* hb_user  = (unsigned short*)take((size_t)MPAD_U * F_ * 2);
  unsigned short* hb_item  = (unsigned short*)take((size_t)MPAD_I * F_ * 2);
  // Wt: [0]=src_u2i [1]=res_u2i [2]=src_i2u [3]=res_i2u, each [512][256] bf16
  unsigned short* Wt  = (unsigned short*)take((size_t)4 * HD_ * F_ * 2);
  unsigned short* wfb = (unsigned short*)take((size_t)2 * 16 * F_ * 2);
  float* el_u2i = (float*)take((size_t)NU_ * 8 * 4);
  float* er_i2u = (float*)take((size_t)NU_ * 8 * 4);
  float* el_i2u = (float*)take((size_t)NI_ * 8 * 4);
  float* er_u2i = (float*)take((size_t)NI_ * 8 * 4);
  int* deg_all      = (int*)take((size_t)SCAN_N * 4);        // zeroed
  int* rowstart_all = (int*)take((size_t)(SCAN_N + 1) * 4);
  int* cursor_all   = (int*)take((size_t)SCAN_N * 4);
  int* bsum         = (int*)take((size_t)128 * 4);
  int* ssrc         = (int*)take((size_t)2 * NE_ * 4);

  hipMemsetAsync(deg_all, 0, (size_t)SCAN_N * 4, stream);

  // copy + wconv + folds + degree histogram (one launch)
  prep_kernel<<<PREP_NB, 256, 0, stream>>>(h_user, h_item,
                                           W_src_u2i, W_res_u2i, W_src_i2u, W_res_i2u,
                                           W_dst_u2i, W_dst_i2u,
                                           al_u2i, ar_u2i, al_i2u, ar_i2u,
                                           dst_u2i, dst_i2u,
                                           hb_user, hb_item, Wt, wfb, deg_all);

  // triple-output GEMM (fs, res, el/er) + scan_reduce tail
  gemm2_kernel<<<GEMM_NB + SCAN_NB, 256, 0, stream>>>(hb_user, hb_item, Wt, wfb,
                                                      fs_u2i, fs_i2u, res_user, res_item,
                                                      bias_u2i, bias_i2u,
                                                      el_u2i, er_i2u, el_i2u, er_u2i,
                                                      deg_all, bsum);

  // CSR: scan + bin
  scan_apply_kernel<<<SCAN_NB, 256, 0, stream>>>(deg_all, bsum, rowstart_all, cursor_all);
  constexpr int EB2 = (2 * NE_ + 255) / 256;
  bin_kernel<<<EB2, 256, 0, stream>>>(src_u2i, dst_u2i, src_i2u, dst_i2u, cursor_all, ssrc);

  // fused online-softmax gather-accumulate + residual, write-only out
  accum_kernel<<<SCAN_N / 4, 256, 0, stream>>>(rowstart_all, ssrc,
                                               el_u2i, el_i2u, er_u2i, er_i2u,
                                               fs_u2i, fs_i2u, res_user, res_item,
                                               out_item, out_user);
}

// Round 9
// 502.002 us; speedup vs baseline: 18.4586x; 1.0120x over previous
//
#include <hip/hip_runtime.h>
#include <cstdint>
#include <cstddef>

// Problem constants
#define NU_ 100000
#define NI_ 50000
#define F_ 256
#define H_ 8
#define HD_ 512
#define NE_ 300000
#define SLOPE_ 0.2f

#define MPAD_U 100096   // NU_ rounded up to 128
#define MPAD_I 50048    // NI_ rounded up to 128
#define MT_U (MPAD_U / 128)   // 782
#define MT_I (MPAD_I / 128)   // 391
#define GEMM_NB ((MT_U + MT_I) * 4)   // 4692

#define SCAN_N (NI_ + NU_)
#define SCAN_CHUNK 2048
#define SCAN_NB ((SCAN_N + SCAN_CHUNK - 1) / SCAN_CHUNK)  // 74

// prep kernel grid split: copy | wconv | fold | hist
#define PREP_COPY_U (NU_ * F_ / 2048)          // 12500
#define PREP_COPY_I (NI_ * F_ / 2048)          // 6250
#define PREP_COPY (PREP_COPY_U + PREP_COPY_I)  // 18750
#define PREP_WCONV 2048
#define PREP_FOLD 32
#define PREP_HIST ((2 * NE_ + 255) / 256)      // 2344
#define PREP_NB (PREP_COPY + PREP_WCONV + PREP_FOLD + PREP_HIST)

typedef float f32x4 __attribute__((ext_vector_type(4)));
typedef __bf16 bf16x8 __attribute__((ext_vector_type(8)));
typedef unsigned short u16x8 __attribute__((ext_vector_type(8)));
typedef unsigned short u16x4 __attribute__((ext_vector_type(4)));

static __device__ __forceinline__ unsigned short f2bf_bits(float f) {
  unsigned u = __float_as_uint(f);
  u += 0x7fffu + ((u >> 16) & 1u);   // RNE
  return (unsigned short)(u >> 16);
}
static __device__ __forceinline__ float bf2f(unsigned short b) {
  return __uint_as_float(((unsigned)b) << 16);
}

// async global->LDS, 16B per lane; dest must be wave-uniform base + lane*16
#define GLL16(g, l)                                                        \
  __builtin_amdgcn_global_load_lds(                                        \
      (const __attribute__((address_space(1))) void*)(g),                  \
      (__attribute__((address_space(3))) void*)(l), 16, 0, 0)

// ---------------- prep: h->bf16 copy + wconv + folds(->bf16 wfb) + degree histogram --
// wfb: [0]=user [16][256] rows 0-7 wl_u2i, 8-15 wr_i2u; [1]=item rows 0-7 wl_i2u, 8-15 wr_u2i
__global__ __launch_bounds__(256) void prep_kernel(const float* __restrict__ h_user,
                                                   const float* __restrict__ h_item,
                                                   const float* __restrict__ W0,
                                                   const float* __restrict__ W1,
                                                   const float* __restrict__ W2,
                                                   const float* __restrict__ W3,
                                                   const float* __restrict__ Wd0,
                                                   const float* __restrict__ Wd1,
                                                   const float* __restrict__ a0,
                                                   const float* __restrict__ a1,
                                                   const float* __restrict__ a2,
                                                   const float* __restrict__ a3,
                                                   const int* __restrict__ dst_u2i,
                                                   const int* __restrict__ dst_i2u,
                                                   unsigned short* __restrict__ hb_user,
                                                   unsigned short* __restrict__ hb_item,
                                                   unsigned short* __restrict__ Wt,
                                                   unsigned short* __restrict__ wfb,
                                                   int* __restrict__ deg) {
  int bid = blockIdx.x;
  if (bid < PREP_COPY) {
    // f32 h -> bf16 hb, 8 elems/thread
    bool user = bid < PREP_COPY_U;
    const float* h = user ? h_user : h_item;
    unsigned short* hb = user ? hb_user : hb_item;
    size_t base = (size_t)(user ? bid : bid - PREP_COPY_U) * 2048 + threadIdx.x * 8;
    f32x4 a = *(const f32x4*)&h[base];
    f32x4 b = *(const f32x4*)&h[base + 4];
    u16x8 o;
    o[0] = f2bf_bits(a.x); o[1] = f2bf_bits(a.y); o[2] = f2bf_bits(a.z); o[3] = f2bf_bits(a.w);
    o[4] = f2bf_bits(b.x); o[5] = f2bf_bits(b.y); o[6] = f2bf_bits(b.z); o[7] = f2bf_bits(b.w);
    *(u16x8*)&hb[base] = o;
  } else if (bid < PREP_COPY + PREP_WCONV) {
    // Wt[m][c][f] = bf16(W_m[f][c]) ; m: 0=src_u2i 1=res_u2i 2=src_i2u 3=res_i2u
    int idx = (bid - PREP_COPY) * 256 + threadIdx.x;
    int m = idx >> 17;
    int r = idx & 131071;
    const float* W = (m == 0) ? W0 : (m == 1) ? W1 : (m == 2) ? W2 : W3;
    int f = r & 255, c = r >> 8;
    Wt[idx] = f2bf_bits(W[(size_t)f * HD_ + c]);
  } else if (bid < PREP_COPY + PREP_WCONV + PREP_FOLD) {
    // fold m: 0=wl_u2i(W0,a0) 1=wr_u2i(Wd0,a1) 2=wl_i2u(W2,a2) 3=wr_i2u(Wd1,a3)
    int b = bid - PREP_COPY - PREP_WCONV;
    int m = b >> 3;
    int idx = (b & 7) * 256 + threadIdx.x;
    const float* W = (m == 0) ? W0 : (m == 1) ? Wd0 : (m == 2) ? W2 : Wd1;
    const float* av = (m == 0) ? a0 : (m == 1) ? a1 : (m == 2) ? a2 : a3;
    int f = idx & 255, hh = idx >> 8;
    float acc = 0.f;
#pragma unroll 8
    for (int d = 0; d < 64; ++d) acc += W[(size_t)f * HD_ + hh * 64 + d] * av[hh * 64 + d];
    int buf = (m == 0 || m == 3) ? 0 : 1;
    int rowoff = (m == 1 || m == 3) ? 8 : 0;
    wfb[buf * 4096 + (rowoff + hh) * 256 + f] = f2bf_bits(acc);
  } else {
    int e = (bid - PREP_COPY - PREP_WCONV - PREP_FOLD) * 256 + threadIdx.x;
    if (e < NE_) atomicAdd(&deg[dst_u2i[e]], 1);
    else if (e < 2 * NE_) atomicAdd(&deg[NI_ + dst_i2u[e - NE_]], 1);
  }
}

// ---------------- triple-output GEMM + scan_reduce tail ------------------------------
// C1 = A@B1 -> bf16 fs;  C2 = A@B2 + bias -> bf16 res;  C3 = A@wf^T -> f32 el/er (nt==0)
// T2 swizzle: LDS dest linear, global SOURCE chunk pre-permuted (slot ^ ((row>>1)&3)),
// reads use the same permutation (rule #21). Counted vmcnt(6) keeps the prefetch tile
// in flight across barriers (no drain-to-0 in the loop). XCD-bijective block swizzle.
__global__ __launch_bounds__(256) void gemm2_kernel(const unsigned short* __restrict__ hb_user,
                                                    const unsigned short* __restrict__ hb_item,
                                                    const unsigned short* __restrict__ Wt,
                                                    const unsigned short* __restrict__ wfb,
                                                    unsigned short* __restrict__ fs_u2i,
                                                    unsigned short* __restrict__ fs_i2u,
                                                    unsigned short* __restrict__ res_user,
                                                    unsigned short* __restrict__ res_item,
                                                    const float* __restrict__ bias_u2i,
                                                    const float* __restrict__ bias_i2u,
                                                    float* __restrict__ el_u2i,
                                                    float* __restrict__ er_i2u,
                                                    float* __restrict__ el_i2u,
                                                    float* __restrict__ er_u2i,
                                                    const int* __restrict__ deg,
                                                    int* __restrict__ bsum) {
  __shared__ unsigned short lds[2][3][128][32];   // 48 KB
  __shared__ unsigned short wflds[2][16][32];     // 2 KB
  if (blockIdx.x >= GEMM_NB) {
    // ---- scan_reduce over deg ----
    int* ilds = (int*)&lds[0][0][0][0];
    int tid = threadIdx.x;
    int base = (blockIdx.x - GEMM_NB) * SCAN_CHUNK + tid * 8;
    int sum = 0;
#pragma unroll
    for (int j = 0; j < 8; ++j) sum += (base + j < SCAN_N) ? deg[base + j] : 0;
    ilds[tid] = sum;
    __syncthreads();
    for (int o = 128; o > 0; o >>= 1) {
      if (tid < o) ilds[tid] += ilds[tid + o];
      __syncthreads();
    }
    if (tid == 0) bsum[blockIdx.x - GEMM_NB] = ilds[0];
    return;
  }
  // XCD-aware bijective remap (m204): consecutive wgid (sharing an A tile) -> same XCD
  int bid;
  {
    constexpr int qq = GEMM_NB / 8, rr = GEMM_NB % 8;   // 586, 4
    int xcd = blockIdx.x & 7, sidx = blockIdx.x >> 3;
    bid = (xcd < rr ? xcd * (qq + 1) : rr * (qq + 1) + (xcd - rr) * qq) + sidx;
  }
  bool user = bid < MT_U * 4;
  if (!user) bid -= MT_U * 4;
  const unsigned short* Ab  = user ? hb_user : hb_item;
  const unsigned short* B1t = user ? (Wt + 0 * HD_ * F_) : (Wt + 2 * HD_ * F_);  // src
  const unsigned short* B2t = user ? (Wt + 3 * HD_ * F_) : (Wt + 1 * HD_ * F_);  // res
  const unsigned short* wfs = user ? wfb : (wfb + 4096);
  unsigned short* fs  = user ? fs_u2i : fs_i2u;
  unsigned short* res = user ? res_user : res_item;
  const float* bias = user ? bias_i2u : bias_u2i;
  int M = user ? NU_ : NI_;

  int tid = threadIdx.x;
  int lane = tid & 63;
  int wave = tid >> 6;
  int wm = wave >> 1, wn = wave & 1;
  int mt = bid >> 2, nt = bid & 3;
  int bm = mt * 128, bn = nt * 128;
  f32x4 acc1[4][4] = {};
  f32x4 acc2[4][4] = {};
  f32x4 acc3[4] = {};
  int lr = lane & 15;
  // T2-swizzled k-slot for fragment reads: slot = (lane>>4) ^ ((row>>1)&3); the row
  // term reduces to (lr>>1)&3 because wm*64, wn*64, m*16, n*16 are all = 0 mod 4 after >>1.
  int ksw = ((lane >> 4) ^ ((lr >> 1) & 3)) << 3;

  int r0 = tid >> 2;                              // staged row 0..63 (and +64)
  int c0 = (tid & 3) << 3;                        // linear LDS dest slot (u16 units)
  int cs = (((tid & 3) ^ ((r0 >> 1) & 3)) << 3);  // swizzled global source slot
  const unsigned short* gA  = &Ab [(size_t)(bm + r0) * 256 + cs];
  const unsigned short* gB1 = &B1t[(size_t)(bn + r0) * 256 + cs];
  const unsigned short* gB2 = &B2t[(size_t)(bn + r0) * 256 + cs];
  const unsigned short* gW  = &wfs[(size_t)(tid >> 2) * 256 + cs];   // valid for tid<64

#define STAGE(buf, t)                                                       \
  do {                                                                      \
    int k0_ = (t) * 32;                                                     \
    GLL16(gA  + k0_,          &lds[buf][0][r0][c0]);                        \
    GLL16(gA  + k0_ + 64*256, &lds[buf][0][r0 + 64][c0]);                   \
    GLL16(gB1 + k0_,          &lds[buf][1][r0][c0]);                        \
    GLL16(gB1 + k0_ + 64*256, &lds[buf][1][r0 + 64][c0]);                   \
    GLL16(gB2 + k0_,          &lds[buf][2][r0][c0]);                        \
    GLL16(gB2 + k0_ + 64*256, &lds[buf][2][r0 + 64][c0]);                   \
    if (nt == 0 && tid < 64) GLL16(gW + k0_, &wflds[buf][tid >> 2][c0]);    \
  } while (0)

  STAGE(0, 0);
#pragma unroll
  for (int t = 0; t < 8; ++t) {
    if (t < 7) STAGE((t + 1) & 1, t + 1);            // prefetch stays in flight
    if (t < 7) asm volatile("s_waitcnt vmcnt(6)" ::: "memory");   // tile t landed
    else       asm volatile("s_waitcnt vmcnt(0)" ::: "memory");
    __builtin_amdgcn_s_barrier();
    __builtin_amdgcn_sched_barrier(0);
    const int cb = t & 1;
    bf16x8 af[4], b1[4], b2[4];
#pragma unroll
    for (int m = 0; m < 4; ++m)
      af[m] = __builtin_bit_cast(bf16x8, *(const u16x8*)&lds[cb][0][wm * 64 + m * 16 + lr][ksw]);
#pragma unroll
    for (int n = 0; n < 4; ++n) {
      b1[n] = __builtin_bit_cast(bf16x8, *(const u16x8*)&lds[cb][1][wn * 64 + n * 16 + lr][ksw]);
      b2[n] = __builtin_bit_cast(bf16x8, *(const u16x8*)&lds[cb][2][wn * 64 + n * 16 + lr][ksw]);
    }
#pragma unroll
    for (int m = 0; m < 4; ++m)
#pragma unroll
      for (int n = 0; n < 4; ++n) {
        acc1[m][n] = __builtin_amdgcn_mfma_f32_16x16x32_bf16(af[m], b1[n], acc1[m][n], 0, 0, 0);
        acc2[m][n] = __builtin_amdgcn_mfma_f32_16x16x32_bf16(af[m], b2[n], acc2[m][n], 0, 0, 0);
      }
    if (nt == 0) {
      bf16x8 b3 = __builtin_bit_cast(bf16x8, *(const u16x8*)&wflds[cb][lr][ksw]);
#pragma unroll
      for (int m = 0; m < 4; ++m)
        acc3[m] = __builtin_amdgcn_mfma_f32_16x16x32_bf16(af[m], b3, acc3[m], 0, 0, 0);
    }
    __builtin_amdgcn_sched_barrier(0);
    __builtin_amdgcn_s_barrier();                    // reads done before next overwrite
  }
#undef STAGE

  int rg = (lane >> 4) * 4;
#pragma unroll
  for (int m = 0; m < 4; ++m) {
#pragma unroll
    for (int r = 0; r < 4; ++r) {
      int row = bm + wm * 64 + m * 16 + rg + r;
      if (row >= M) continue;
#pragma unroll
      for (int n = 0; n < 4; ++n) {
        int col = bn + wn * 64 + n * 16 + lr;
        fs[(size_t)row * HD_ + col]  = f2bf_bits(acc1[m][n][r]);
        res[(size_t)row * HD_ + col] = f2bf_bits(acc2[m][n][r] + bias[col]);
      }
    }
  }
  if (nt == 0 && wn == 0) {
    float* elp = user ? el_u2i : el_i2u;
    float* erp = user ? er_i2u : er_u2i;
#pragma unroll
    for (int m = 0; m < 4; ++m) {
#pragma unroll
      for (int r = 0; r < 4; ++r) {
        int row = bm + wm * 64 + m * 16 + rg + r;
        if (row >= M) continue;
        if (lr < 8) elp[(size_t)row * 8 + lr] = acc3[m][r];
        else        erp[(size_t)row * 8 + lr - 8] = acc3[m][r];
      }
    }
  }
}

// ---------------- scan_apply (self-scans the 74 block sums) --------------------------
__global__ __launch_bounds__(256) void scan_apply_kernel(const int* __restrict__ deg,
                                                         const int* __restrict__ bsum,
                                                         int* __restrict__ rowstart,
                                                         int* __restrict__ cursor) {
  __shared__ int sb[128];
  __shared__ int lds[256];
  int tid = threadIdx.x;
  if (tid < 128) sb[tid] = (tid < SCAN_NB) ? bsum[tid] : 0;
  __syncthreads();
  for (int o = 1; o < 128; o <<= 1) {
    int t = (tid < 128 && tid >= o) ? sb[tid - o] : 0;
    __syncthreads();
    if (tid < 128) sb[tid] += t;
    __syncthreads();
  }
  int blockpref = (blockIdx.x == 0) ? 0 : sb[blockIdx.x - 1];
  int base = blockIdx.x * SCAN_CHUNK + tid * 8;
  int v[8];
  int sum = 0;
#pragma unroll
  for (int j = 0; j < 8; ++j) {
    v[j] = (base + j < SCAN_N) ? deg[base + j] : 0;
    sum += v[j];
  }
  lds[tid] = sum;
  __syncthreads();
  for (int o = 1; o < 256; o <<= 1) {
    int t = (tid >= o) ? lds[tid - o] : 0;
    __syncthreads();
    lds[tid] += t;
    __syncthreads();
  }
  int run = blockpref + lds[tid] - sum;
#pragma unroll
  for (int j = 0; j < 8; ++j) {
    if (base + j < SCAN_N) { rowstart[base + j] = run; cursor[base + j] = run; }
    run += v[j];
  }
  if (blockIdx.x == 0 && tid == 0) rowstart[SCAN_N] = 2 * NE_;
}

// ---------------- bin: scatter source node ids into CSR slots ----------------
__global__ __launch_bounds__(256) void bin_kernel(const int* __restrict__ src_u2i,
                                                  const int* __restrict__ dst_u2i,
                                                  const int* __restrict__ src_i2u,
                                                  const int* __restrict__ dst_i2u,
                                                  int* __restrict__ cursor,
                                                  int* __restrict__ ssrc) {
  int e = blockIdx.x * 256 + threadIdx.x;
  int de, se;
  if (e < NE_) { de = dst_u2i[e]; se = src_u2i[e]; }
  else if (e < 2 * NE_) { de = NI_ + dst_i2u[e - NE_]; se = src_i2u[e - NE_]; }
  else return;
  int pos = atomicAdd(&cursor[de], 1);
  ssrc[pos] = se;
}

// ---------------- fused accum: online softmax + weighted fs gather + residual --------
__global__ __launch_bounds__(256) void accum_kernel(const int* __restrict__ rowstart,
                                                    const int* __restrict__ ssrc,
                                                    const float* __restrict__ el_u2i,
                                                    const float* __restrict__ el_i2u,
                                                    const float* __restrict__ er_u2i,
                                                    const float* __restrict__ er_i2u,
                                                    const unsigned short* __restrict__ fs_u2i,
                                                    const unsigned short* __restrict__ fs_i2u,
                                                    const unsigned short* __restrict__ res_user,
                                                    const unsigned short* __restrict__ res_item,
                                                    float* __restrict__ out_item,
                                                    float* __restrict__ out_user) {
  int n = blockIdx.x * 4 + (threadIdx.x >> 6);
  int lane = threadIdx.x & 63;
  bool item = n < NI_;
  int ln = item ? n : n - NI_;
  const unsigned short* res = item ? res_item : res_user;
  float* out = (item ? out_item : out_user) + (size_t)ln * HD_;
  int r0 = rowstart[n], r1 = rowstart[n + 1];
  float acc[8] = {};
  if (r0 < r1) {
    const float* el = item ? el_u2i : el_i2u;
    const float* er = item ? er_u2i : er_i2u;
    const unsigned short* fs = item ? fs_u2i : fs_i2u;
    int hh = lane >> 3;
    float erh = er[(size_t)ln * 8 + hh];
    float m = -3.0e38f, s = 0.f;
    int k = r0;
    for (; k + 2 <= r1; k += 2) {
      int s0 = ssrc[k], s1 = ssrc[k + 1];
      float e0 = el[(size_t)s0 * 8 + hh] + erh;
      float e1 = el[(size_t)s1 * 8 + hh] + erh;
      e0 = e0 > 0.f ? e0 : SLOPE_ * e0;
      e1 = e1 > 0.f ? e1 : SLOPE_ * e1;
      u16x8 v0 = *(const u16x8*)&fs[(size_t)s0 * HD_ + lane * 8];
      u16x8 v1 = *(const u16x8*)&fs[(size_t)s1 * HD_ + lane * 8];
      float mm = fmaxf(e0, e1);
      if (mm > m) {
        float r = __expf(m - mm);
        s *= r;
#pragma unroll
        for (int j = 0; j < 8; ++j) acc[j] *= r;
        m = mm;
      }
      float x0 = __expf(e0 - m), x1 = __expf(e1 - m);
      s += x0 + x1;
#pragma unroll
      for (int j = 0; j < 8; ++j)
        acc[j] += x0 * bf2f((unsigned short)v0[j]) + x1 * bf2f((unsigned short)v1[j]);
    }
    if (k < r1) {
      int s0 = ssrc[k];
      float e0 = el[(size_t)s0 * 8 + hh] + erh;
      e0 = e0 > 0.f ? e0 : SLOPE_ * e0;
      u16x8 v0 = *(const u16x8*)&fs[(size_t)s0 * HD_ + lane * 8];
      if (e0 > m) {
        float r = __expf(m - e0);
        s *= r;
#pragma unroll
        for (int j = 0; j < 8; ++j) acc[j] *= r;
        m = e0;
      }
      float x0 = __expf(e0 - m);
      s += x0;
#pragma unroll
      for (int j = 0; j < 8; ++j) acc[j] += x0 * bf2f((unsigned short)v0[j]);
    }
    float inv = 1.f / s;
#pragma unroll
    for (int j = 0; j < 8; ++j) acc[j] *= inv;
  }
  u16x8 rv = *(const u16x8*)&res[(size_t)ln * HD_ + lane * 8];
  f32x4 o0, o1;
#pragma unroll
  for (int j = 0; j < 4; ++j) {
    o0[j] = acc[j] + bf2f((unsigned short)rv[j]);
    o1[j] = acc[4 + j] + bf2f((unsigned short)rv[4 + j]);
  }
  float* op = out + lane * 8;
  *(f32x4*)op = o0;
  *(f32x4*)(op + 4) = o1;
}

// =====================================================================================
extern "C" void kernel_launch(void* const* d_in, const int* in_sizes, int n_in,
                              void* d_out, int out_size, void* d_ws, size_t ws_size,
                              hipStream_t stream) {
  const float* h_user    = (const float*)d_in[0];
  const float* h_item    = (const float*)d_in[1];
  const int*   src_u2i   = (const int*)d_in[2];
  const int*   dst_u2i   = (const int*)d_in[3];
  const int*   src_i2u   = (const int*)d_in[4];
  const int*   dst_i2u   = (const int*)d_in[5];
  const float* W_src_u2i = (const float*)d_in[6];
  const float* W_dst_u2i = (const float*)d_in[7];
  const float* al_u2i    = (const float*)d_in[8];
  const float* ar_u2i    = (const float*)d_in[9];
  const float* bias_u2i  = (const float*)d_in[10];
  const float* W_res_u2i = (const float*)d_in[11];
  const float* W_src_i2u = (const float*)d_in[12];
  const float* W_dst_i2u = (const float*)d_in[13];
  const float* al_i2u    = (const float*)d_in[14];
  const float* ar_i2u    = (const float*)d_in[15];
  const float* bias_i2u  = (const float*)d_in[16];
  const float* W_res_i2u = (const float*)d_in[17];

  float* out_user = (float*)d_out;                       // [NU,512]
  float* out_item = (float*)d_out + (size_t)NU_ * HD_;   // [NI,512]

  char* ws = (char*)d_ws;
  size_t off = 0;
  auto take = [&](size_t bytes) -> char* {
    char* p = ws + off;
    off += (bytes + 255) & ~(size_t)255;
    return p;
  };
  unsigned short* fs_u2i   = (unsigned short*)take((size_t)NU_ * HD_ * 2);
  unsigned short* fs_i2u   = (unsigned short*)take((size_t)NI_ * HD_ * 2);
  unsigned short* res_user = (unsigned short*)take((size_t)NU_ * HD_ * 2);
  unsigned short* res_item = (unsigned short*)take((size_t)NI_ * HD_ * 2);
  unsigned short* hb_user  = (unsigned short*)take((size_t)MPAD_U * F_ * 2);
  unsigned short* hb_item  = (unsigned short*)take((size_t)MPAD_I * F_ * 2);
  // Wt: [0]=src_u2i [1]=res_u2i [2]=src_i2u [3]=res_i2u, each [512][256] bf16
  unsigned short* Wt  = (unsigned short*)take((size_t)4 * HD_ * F_ * 2);
  unsigned short* wfb = (unsigned short*)take((size_t)2 * 16 * F_ * 2);
  float* el_u2i = (float*)take((size_t)NU_ * 8 * 4);
  float* er_i2u = (float*)take((size_t)NU_ * 8 * 4);
  float* el_i2u = (float*)take((size_t)NI_ * 8 * 4);
  float* er_u2i = (float*)take((size_t)NI_ * 8 * 4);
  int* deg_all      = (int*)take((size_t)SCAN_N * 4);        // zeroed
  int* rowstart_all = (int*)take((size_t)(SCAN_N + 1) * 4);
  int* cursor_all   = (int*)take((size_t)SCAN_N * 4);
  int* bsum         = (int*)take((size_t)128 * 4);
  int* ssrc         = (int*)take((size_t)2 * NE_ * 4);

  hipMemsetAsync(deg_all, 0, (size_t)SCAN_N * 4, stream);

  // copy + wconv + folds + degree histogram (one launch)
  prep_kernel<<<PREP_NB, 256, 0, stream>>>(h_user, h_item,
                                           W_src_u2i, W_res_u2i, W_src_i2u, W_res_i2u,
                                           W_dst_u2i, W_dst_i2u,
                                           al_u2i, ar_u2i, al_i2u, ar_i2u,
                                           dst_u2i, dst_i2u,
                                           hb_user, hb_item, Wt, wfb, deg_all);

  // triple-output GEMM (fs, res, el/er) + scan_reduce tail
  gemm2_kernel<<<GEMM_NB + SCAN_NB, 256, 0, stream>>>(hb_user, hb_item, Wt, wfb,
                                                      fs_u2i, fs_i2u, res_user, res_item,
                                                      bias_u2i, bias_i2u,
                                                      el_u2i, er_i2u, el_i2u, er_u2i,
                                                      deg_all, bsum);

  // CSR: scan + bin
  scan_apply_kernel<<<SCAN_NB, 256, 0, stream>>>(deg_all, bsum, rowstart_all, cursor_all);
  constexpr int EB2 = (2 * NE_ + 255) / 256;
  bin_kernel<<<EB2, 256, 0, stream>>>(src_u2i, dst_u2i, src_i2u, dst_i2u, cursor_all, ssrc);

  // fused online-softmax gather-accumulate + residual, write-only out
  accum_kernel<<<SCAN_N / 4, 256, 0, stream>>>(rowstart_all, ssrc,
                                               el_u2i, el_i2u, er_u2i, er_i2u,
                                               fs_u2i, fs_i2u, res_user, res_item,
                                               out_item, out_user);
}